// Round 10
// baseline (827.406 us; speedup 1.0000x reference)
//
#include <hip/hip_runtime.h>

#define NODES 25088
#define NB 8
#define NPB 3136   // nodes per batch (56*56)
#define C 96
#define KNN 9
#define COUT 192
#define MSPLIT 4   // m-range quarters for knn filter
#define T12 12     // filter depth per quarter (>= 10 guarantees exact top-9 coverage)
#define NCAND (MSPLIT * T12)  // 48 rescore candidates per query

typedef float f32x4 __attribute__((ext_vector_type(4)));
typedef float f32x16 __attribute__((ext_vector_type(16)));
typedef short s16x8 __attribute__((ext_vector_type(8)));

__device__ __forceinline__ unsigned short f2bf(float x) {
  unsigned u = __float_as_uint(x);
  return (unsigned short)((u + 0x7fffu + ((u >> 16) & 1u)) >> 16);
}
__device__ __forceinline__ float bf2f(unsigned short h) {
  return __uint_as_float(((unsigned)h) << 16);
}

// ---------------- transpose x [B,C,N] -> xf [B*N, C] ----------------
__global__ void transpose_kernel(const float* __restrict__ x, float* __restrict__ xf) {
  __shared__ float t[32][33];
  int b = blockIdx.z, ct = blockIdx.y, nt = blockIdx.x;
  int tx = threadIdx.x, ty = threadIdx.y;
  int n0 = nt * 32, c0 = ct * 32;
  const float* xb = x + (size_t)b * C * NPB;
#pragma unroll
  for (int i = 0; i < 4; i++) {
    int c = c0 + ty + i * 8;
    t[ty + i * 8][tx] = xb[(size_t)c * NPB + n0 + tx];
  }
  __syncthreads();
  float* xfb = xf + (size_t)b * NPB * C;
#pragma unroll
  for (int i = 0; i < 4; i++) {
    int n = n0 + ty + i * 8;
    xfb[(size_t)n * C + c0 + tx] = t[tx][ty + i * 8];
  }
}

// ---------------- per-node squared norm ----------------
__global__ void sq_kernel(const float* __restrict__ xf, float* __restrict__ sq) {
  int node = blockIdx.x * 256 + threadIdx.x;
  const float4* r = (const float4*)(xf + (size_t)node * C);
  float s = 0.f;
#pragma unroll
  for (int i = 0; i < 24; i++) {
    float4 v = r[i];
    s += v.x * v.x + v.y * v.y + v.z * v.z + v.w * v.w;
  }
  sq[node] = s;
}

// ---------------- fp32 -> bf16 hi/lo split ----------------
__global__ void split_kernel(const float* __restrict__ xf,
                             unsigned short* __restrict__ xh,
                             unsigned short* __restrict__ xl) {
  int i = blockIdx.x * 256 + threadIdx.x;  // one float4 per thread
  float4 v = ((const float4*)xf)[i];
  ushort4 h, l;
  h.x = f2bf(v.x); l.x = f2bf(v.x - bf2f(h.x));
  h.y = f2bf(v.y); l.y = f2bf(v.y - bf2f(h.y));
  h.z = f2bf(v.z); l.z = f2bf(v.z - bf2f(h.z));
  h.w = f2bf(v.w); l.w = f2bf(v.w - bf2f(h.w));
  ((ushort4*)xh)[i] = h;
  ((ushort4*)xl)[i] = l;
}

// ---------------- small weight-fold helpers (run once per launch, ~us) ----------------
// C[M,N] = A[M,K] @ B[K,N], one thread per output element.
__global__ void smallmm_kernel(const float* __restrict__ A, const float* __restrict__ B,
                               float* __restrict__ Cc, int M, int K, int N) {
  int t = blockIdx.x * 256 + threadIdx.x;
  if (t >= M * N) return;
  int m = t / N, n = t % N;
  float acc = 0.f;
  for (int k = 0; k < K; k++) acc += A[m * K + k] * B[k * N + n];
  Cc[t] = acc;
}

// outb[n] = sum_k a[k]*B[k,n] + c[n]
__global__ void biasfold_kernel(const float* __restrict__ a, const float* __restrict__ B,
                                const float* __restrict__ c, float* __restrict__ outb,
                                int K, int N) {
  int n = blockIdx.x * 256 + threadIdx.x;
  if (n >= N) return;
  float acc = c[n];
  for (int k = 0; k < K; k++) acc += a[k] * B[k * N + n];
  outb[n] = acc;
}

// bP[n] = sum_k io_b[k]*up_w[k,n] + sum_k fc_b[k]*up_w[192+k,n] + up_b[n]
__global__ void finalbias_kernel(const float* __restrict__ io_b, const float* __restrict__ fc_b,
                                 const float* __restrict__ up_w, const float* __restrict__ up_b,
                                 float* __restrict__ outb) {
  int n = threadIdx.x;  // 192
  float acc = up_b[n];
  for (int k = 0; k < 192; k++) {
    acc += io_b[k] * up_w[k * 192 + n];
    acc += fc_b[k] * up_w[(192 + k) * 192 + n];
  }
  outb[n] = acc;
}

// ---------------- logits = h64 @ WdP + bdP; kint = argmax (first max) ----------------
__global__ void argmax9_kernel(const float* __restrict__ h64, const float* __restrict__ WdP,
                               const float* __restrict__ bdP, int* __restrict__ kint,
                               float* __restrict__ rs) {
  __shared__ float wd[64 * 9];
  __shared__ float bd[9];
  int tid = threadIdx.x;
  for (int f = tid; f < 576; f += 256) wd[f] = WdP[f];
  if (tid < 9) bd[tid] = bdP[tid];
  __syncthreads();
  int node = blockIdx.x * 256 + tid;
  const float4* hp = (const float4*)(h64 + (size_t)node * 64);
  float4 h[16];
#pragma unroll
  for (int i = 0; i < 16; i++) h[i] = hp[i];
  float best = -3.4e38f;
  int bi = 0;
#pragma unroll
  for (int n = 0; n < 9; n++) {
    float acc = bd[n];
#pragma unroll
    for (int k = 0; k < 16; k++) {
      float4 hv = h[k];
      acc += hv.x * wd[(4 * k + 0) * 9 + n] + hv.y * wd[(4 * k + 1) * 9 + n] +
             hv.z * wd[(4 * k + 2) * 9 + n] + hv.w * wd[(4 * k + 3) * 9 + n];
    }
    if (acc > best) { best = acc; bi = n; }
  }
  kint[node] = bi;
  rs[node] = (float)bi;
}

// ---------------- MFMA kNN filter: approx top-12 per m-quarter per query ----------------
__global__ __launch_bounds__(256) void knn_mfma_kernel(
    const unsigned short* __restrict__ xh, const unsigned short* __restrict__ xl,
    const float* __restrict__ sq, int* __restrict__ pk_i) {
  __shared__ unsigned short mh[64 * 104];   // 13312 B (bf16-hi m-tile)
  __shared__ float ST[64 * 68];             // 17408 B (S transposed: [m][q])
  __shared__ float sqs[64];
  int tid = threadIdx.x;
  int lane = tid & 63, wv = tid >> 6;
  int b = blockIdx.y, z = blockIdx.z;
  int q0 = blockIdx.x * 64;
  int bbase = b * NPB;
  int t0 = (z * 49) / MSPLIT, t1 = ((z + 1) * 49) / MSPLIT;

  int koff = (lane >> 5) * 8;
  int rowA = bbase + q0 + (wv >> 1) * 32 + (lane & 31);
  s16x8 ah[6], al[6];
  {
    const unsigned short* ph = xh + (size_t)rowA * 96 + koff;
    const unsigned short* pl = xl + (size_t)rowA * 96 + koff;
#pragma unroll
    for (int kc = 0; kc < 6; kc++) {
      ah[kc] = *(const s16x8*)(ph + kc * 16);
      al[kc] = *(const s16x8*)(pl + kc * 16);
    }
  }
  float sqr = sq[bbase + q0 + lane];  // scan role: lane = query

  float fd[T12];
#pragma unroll
  for (int k = 0; k < T12; k++) fd[k] = 3.4e38f;

  int srow = tid >> 2, sseg = tid & 3;

  for (int t = t0; t < t1; t++) {
    int m0 = t * 64;
    __syncthreads();
    {
      const unsigned short* gh = xh + (size_t)(bbase + m0 + srow) * 96;
#pragma unroll
      for (int i = 0; i < 3; i++) {
        int s = sseg * 3 + i;
        *(s16x8*)(mh + srow * 104 + s * 8) = *(const s16x8*)(gh + s * 8);
      }
      if (tid < 64) sqs[tid] = sq[bbase + m0 + tid];
    }
    __syncthreads();

    int mrow = (wv & 1) * 32 + (lane & 31);
    s16x8 bh[6];
#pragma unroll
    for (int kc = 0; kc < 6; kc++)
      bh[kc] = *(const s16x8*)(mh + mrow * 104 + kc * 16 + koff);

    f32x16 acc = (f32x16){0.f, 0.f, 0.f, 0.f, 0.f, 0.f, 0.f, 0.f,
                          0.f, 0.f, 0.f, 0.f, 0.f, 0.f, 0.f, 0.f};
    asm volatile(
        "s_nop 1\n\t"
        "v_mfma_f32_32x32x16_bf16 %0, %1, %13, %0\n\t"
        "v_mfma_f32_32x32x16_bf16 %0, %7, %13, %0\n\t"
        "v_mfma_f32_32x32x16_bf16 %0, %2, %14, %0\n\t"
        "v_mfma_f32_32x32x16_bf16 %0, %8, %14, %0\n\t"
        "v_mfma_f32_32x32x16_bf16 %0, %3, %15, %0\n\t"
        "v_mfma_f32_32x32x16_bf16 %0, %9, %15, %0\n\t"
        "v_mfma_f32_32x32x16_bf16 %0, %4, %16, %0\n\t"
        "v_mfma_f32_32x32x16_bf16 %0, %10, %16, %0\n\t"
        "v_mfma_f32_32x32x16_bf16 %0, %5, %17, %0\n\t"
        "v_mfma_f32_32x32x16_bf16 %0, %11, %17, %0\n\t"
        "v_mfma_f32_32x32x16_bf16 %0, %6, %18, %0\n\t"
        "v_mfma_f32_32x32x16_bf16 %0, %12, %18, %0\n\t"
        "s_nop 7\n\t"
        "s_nop 7\n\t"
        "s_nop 7"
        : "+v"(acc)
        : "v"(ah[0]), "v"(ah[1]), "v"(ah[2]), "v"(ah[3]), "v"(ah[4]), "v"(ah[5]),
          "v"(al[0]), "v"(al[1]), "v"(al[2]), "v"(al[3]), "v"(al[4]), "v"(al[5]),
          "v"(bh[0]), "v"(bh[1]), "v"(bh[2]), "v"(bh[3]), "v"(bh[4]), "v"(bh[5]));

    {
      int mcol = (wv & 1) * 32 + (lane & 31);
      int qbase = (wv >> 1) * 32 + 4 * (lane >> 5);
#pragma unroll
      for (int g = 0; g < 4; g++) {
        f32x4 v = (f32x4){acc[4 * g + 0], acc[4 * g + 1], acc[4 * g + 2], acc[4 * g + 3]};
        *(f32x4*)(ST + mcol * 68 + qbase + 8 * g) = v;
      }
    }
    __syncthreads();

    int lbase = (t - t0) * 64;
#pragma unroll
    for (int i = 0; i < 16; i++) {
      int mloc = wv * 16 + i;
      float d = fmaf(-2.f, ST[mloc * 68 + lane], sqr + sqs[mloc]);
      unsigned u = (__float_as_uint(d) & 0xFFFFFC00u) | (unsigned)(lbase + mloc);
      float key = __uint_as_float(u);
      if (key < fd[T12 - 1]) {
        float t2 = key;
#pragma unroll
        for (int k = 0; k < T12; k++) {
          float lo = fminf(fd[k], t2);
          t2 = fmaxf(fd[k], t2);
          fd[k] = lo;
        }
      }
    }
  }

  __syncthreads();
  float* cd = (float*)mh;
#pragma unroll
  for (int k = 0; k < T12; k++) cd[(wv * 64 + lane) * T12 + k] = fd[k];
  __syncthreads();
  if (wv == 0) {
    float gd[T12];
#pragma unroll
    for (int k = 0; k < T12; k++) gd[k] = 3.4e38f;
    for (int s = 0; s < 4; s++) {
#pragma unroll
      for (int k = 0; k < T12; k++) {
        float key = cd[(s * 64 + lane) * T12 + k];
        if (key < gd[T12 - 1]) {
          float t2 = key;
#pragma unroll
          for (int kk = 0; kk < T12; kk++) {
            float lo = fminf(gd[kk], t2);
            t2 = fmaxf(gd[kk], t2);
            gd[kk] = lo;
          }
        }
      }
    }
    size_t base = ((size_t)(bbase + q0 + lane) * MSPLIT + z) * T12;
#pragma unroll
    for (int k = 0; k < T12; k++) {
      int mloc = (int)(__float_as_uint(gd[k]) & 0x3FFu) + t0 * 64;
      pk_i[base + k] = bbase + mloc;
    }
  }
}

// ---------------- exact fp32 rescore of NCAND candidates -> top-9 ----------------
__global__ void rescore_kernel(const float* __restrict__ xf, const float* __restrict__ sq,
                               const int* __restrict__ pk_i, int* __restrict__ nn) {
  __shared__ float qr[4][96];
  __shared__ float sqq[4];
  __shared__ float dd[4][NCAND];
  __shared__ int jj[4][NCAND];
  int tid = threadIdx.x;
  int qloc = tid >> 6, c = tid & 63;
  int qbase = blockIdx.x * 4;
  for (int f = tid; f < 4 * 96; f += 256)
    qr[f / 96][f % 96] = xf[(size_t)(qbase + f / 96) * 96 + f % 96];
  if (tid < 4) sqq[tid] = sq[qbase + tid];
  __syncthreads();
  if (c < NCAND) {
    int q = qbase + qloc;
    int j = pk_i[(size_t)q * NCAND + c];
    const float4* qp = (const float4*)qr[qloc];
    const float4* mp = (const float4*)(xf + (size_t)j * 96);
    float d0 = 0.f, d1 = 0.f, d2 = 0.f, d3 = 0.f;
#pragma unroll
    for (int i = 0; i < 24; i++) {
      float4 qv = qp[i];
      float4 mv = mp[i];
      d0 += qv.x * mv.x;
      d1 += qv.y * mv.y;
      d2 += qv.z * mv.z;
      d3 += qv.w * mv.w;
    }
    dd[qloc][c] = (sqq[qloc] - 2.0f * ((d0 + d1) + (d2 + d3))) + sq[j];
    jj[qloc][c] = j;
  }
  __syncthreads();
  if (c == 0) {
    int q = qbase + qloc;
    float fd[KNN];
    int fi[KNN];
#pragma unroll
    for (int k = 0; k < KNN; k++) { fd[k] = 3.4e38f; fi[k] = 0x7fffffff; }
    for (int e = 0; e < NCAND; e++) {
      float d = dd[qloc][e];
      int j = jj[qloc][e];
      if (d < fd[KNN - 1] || (d == fd[KNN - 1] && j < fi[KNN - 1])) {
        fd[KNN - 1] = d;
        fi[KNN - 1] = j;
#pragma unroll
        for (int k = KNN - 1; k > 0; --k) {
          bool sw = (fd[k] < fd[k - 1]) || (fd[k] == fd[k - 1] && fi[k] < fi[k - 1]);
          if (sw) {
            float td = fd[k]; fd[k] = fd[k - 1]; fd[k - 1] = td;
            int ti = fi[k]; fi[k] = fi[k - 1]; fi[k - 1] = ti;
          }
        }
      }
    }
#pragma unroll
    for (int k = 0; k < KNN; k++) nn[(size_t)q * KNN + k] = fi[k];
  }
}

// ---------------- gather-sum of kept neighbors ----------------
__global__ void gather_kernel(const float* __restrict__ feat, const int* __restrict__ nn,
                              const int* __restrict__ kint, float* __restrict__ out) {
  int idx = blockIdx.x * 256 + threadIdx.x;
  int node = idx / 24, c4 = idx % 24;
  int kc = kint[node];
  const int* nr = nn + (size_t)node * KNN;
  float4 acc = make_float4(0.f, 0.f, 0.f, 0.f);
  for (int k = 0; k < kc; k++) {
    int j = nr[k];
    float4 v = ((const float4*)(feat + (size_t)j * C))[c4];
    acc.x += v.x; acc.y += v.y; acc.z += v.z; acc.w += v.w;
  }
  ((float4*)(out + (size_t)node * C))[c4] = acc;
}

// ---------------- generic fp32 GEMM ----------------
__global__ __launch_bounds__(256) void gemm_kernel(
    const float* __restrict__ A0, const float* __restrict__ A1, int K0, int Ktot,
    const float* __restrict__ sc0, const float* __restrict__ sc1,
    const float* __restrict__ B, int ldb, int bmode,
    const float* __restrict__ bias, const float* __restrict__ bscale,
    float* __restrict__ Cc, int M, int N, int relu, int tstore) {
  __shared__ float As[16][68];
  __shared__ float Bs[16][68];
  int tid = threadIdx.x;
  int tx = tid & 15, ty = tid >> 4;
  int row0 = blockIdx.x * 64, col0 = blockIdx.y * 64;
  float acc[4][4] = {};
  int ai = tid >> 2;
  int ak = (tid & 3) * 4;
  int bk = tid >> 4;
  int bj = (tid & 15) * 4;
  bool edge = (col0 + 64 > N);

  for (int k0 = 0; k0 < Ktot; k0 += 16) {
    {
      const float* Ap;
      const float* sc;
      int lda, kk;
      if (k0 < K0) { Ap = A0; lda = K0; sc = sc0; kk = k0; }
      else { Ap = A1; lda = Ktot - K0; sc = sc1; kk = k0 - K0; }
      int r = row0 + ai;
      float4 v = *(const float4*)(Ap + (size_t)r * lda + kk + ak);
      if (sc) { float s = sc[r]; v.x *= s; v.y *= s; v.z *= s; v.w *= s; }
      As[ak + 0][ai] = v.x;
      As[ak + 1][ai] = v.y;
      As[ak + 2][ai] = v.z;
      As[ak + 3][ai] = v.w;
    }
    {
      int kg = k0 + bk;
      int j = col0 + bj;
      float4 v;
      if (!edge) {
        v = *(const float4*)(B + (size_t)kg * ldb + j);
        if (bmode == 1 && kg < 96) {
          float4 w = *(const float4*)(B + (size_t)(kg + 96) * ldb + j);
          v.x -= w.x; v.y -= w.y; v.z -= w.z; v.w -= w.w;
        }
      } else {
        float tmp[4];
#pragma unroll
        for (int e = 0; e < 4; e++) {
          int jjx = j + e;
          float val = 0.f;
          if (jjx < N) {
            val = B[(size_t)kg * ldb + jjx];
            if (bmode == 1 && kg < 96) val -= B[(size_t)(kg + 96) * ldb + jjx];
          }
          tmp[e] = val;
        }
        v = make_float4(tmp[0], tmp[1], tmp[2], tmp[3]);
      }
      *(float4*)&Bs[bk][bj] = v;
    }
    __syncthreads();
#pragma unroll
    for (int kk = 0; kk < 16; kk++) {
      float4 av = *(const float4*)&As[kk][ty * 4];
      float4 bv = *(const float4*)&Bs[kk][tx * 4];
      acc[0][0] += av.x * bv.x; acc[0][1] += av.x * bv.y; acc[0][2] += av.x * bv.z; acc[0][3] += av.x * bv.w;
      acc[1][0] += av.y * bv.x; acc[1][1] += av.y * bv.y; acc[1][2] += av.y * bv.z; acc[1][3] += av.y * bv.w;
      acc[2][0] += av.z * bv.x; acc[2][1] += av.z * bv.y; acc[2][2] += av.z * bv.z; acc[2][3] += av.z * bv.w;
      acc[3][0] += av.w * bv.x; acc[3][1] += av.w * bv.y; acc[3][2] += av.w * bv.z; acc[3][3] += av.w * bv.w;
    }
    __syncthreads();
  }
#pragma unroll
  for (int ii = 0; ii < 4; ii++) {
    int r = row0 + ty * 4 + ii;
    float bsv = bscale ? bscale[r] : 1.f;
#pragma unroll
    for (int jjx = 0; jjx < 4; jjx++) {
      int j = col0 + tx * 4 + jjx;
      if (edge && j >= N) continue;
      float v = acc[ii][jjx];
      if (bias) v += bsv * bias[j];
      if (relu) v = fmaxf(v, 0.f);
      if (tstore) {
        int bb = r / NPB, n = r % NPB;
        Cc[(size_t)bb * COUT * NPB + (size_t)j * NPB + n] = v;
      } else {
        Cc[(size_t)r * N + j] = v;
      }
    }
  }
}

extern "C" void kernel_launch(void* const* d_in, const int* in_sizes, int n_in,
                              void* d_out, int out_size, void* d_ws, size_t ws_size,
                              hipStream_t stream) {
  const float* x      = (const float*)d_in[0];
  const float* kmap_w = (const float*)d_in[1];
  const float* kmap_b = (const float*)d_in[2];
  const float* kfc_w  = (const float*)d_in[3];
  const float* kfc_b  = (const float*)d_in[4];
  const float* kmu_w  = (const float*)d_in[5];
  const float* kmu_b  = (const float*)d_in[6];
  const float* kdec_w = (const float*)d_in[7];
  const float* kdec_b = (const float*)d_in[8];
  const float* ec1_w  = (const float*)d_in[9];
  const float* ec1_b  = (const float*)d_in[10];
  const float* ec2_w  = (const float*)d_in[11];
  const float* ec2_b  = (const float*)d_in[12];
  const float* fc_w   = (const float*)d_in[13];
  const float* fc_b   = (const float*)d_in[14];
  const float* io_w   = (const float*)d_in[15];
  const float* io_b   = (const float*)d_in[16];
  const float* up_w   = (const float*)d_in[17];
  const float* up_b   = (const float*)d_in[18];

  // ---- workspace layout (liveness-aliased) ----
  char* ws = (char*)d_ws;
  size_t off = 0;
  auto alloc = [&](size_t bytes) -> void* {
    void* p = ws + off;
    off += (bytes + 255) & ~(size_t)255;
    return p;
  };
  float* xf    = (float*)alloc((size_t)NODES * C * 4);   // live until final GEMM
  float* sqb   = (float*)alloc((size_t)NODES * 4);
  float* rs    = (float*)alloc((size_t)NODES * 4);
  int*   kint  = (int*)alloc((size_t)NODES * 4);
  int*   nn    = (int*)alloc((size_t)NODES * KNN * 4);
  float* bufH1 = (float*)alloc((size_t)NODES * C * 4);
  float* bufS  = (float*)alloc((size_t)NODES * C * 4);
  char*  region = (char*)alloc((size_t)NODES * COUT * 4);  // 19.27 MB shared region
  // region timeline: h64buf (6.4MB) -> pk_i (4.8MB) -> bufH2 (9.6MB); all serial.
  float* h64buf = (float*)region;
  int*   pk_i   = (int*)region;
  float* bufH2  = (float*)region;
  // fold weights at region+12MB (176KB; never overlaps the above)
  char* wbase = region + 12 * 1024 * 1024;
  float* WkP = (float*)wbase;                  // [96,64]
  float* bkP = WkP + 96 * 64;                  // [64]
  float* WdP = bkP + 64;                       // [64,9]
  float* bdP = WdP + 64 * 9;                   // [9]
  float* WPf = bdP + 16;                       // [192,192] (rows 0-95 = W1', 96-191 = W2')
  float* bPf = WPf + 192 * 192;                // [192]
  unsigned short* xh = (unsigned short*)bufH1;  // bf16 hi; dead after knn
  unsigned short* xl = (unsigned short*)bufS;   // bf16 lo; dead after knn
  float* bufAgg = bufH1;  // unused name kept out; (bufH1 reused normally below)
  (void)bufAgg;

  transpose_kernel<<<dim3(98, 3, 8), dim3(32, 8), 0, stream>>>(x, xf);
  sq_kernel<<<98, 256, 0, stream>>>(xf, sqb);
  split_kernel<<<2352, 256, 0, stream>>>(xf, xh, xl);

  // ---- VAE fold: Wk' = kmap_w@kfc_w, Wd' = kmu_w@kdec_w (+bias folds) ----
  smallmm_kernel<<<24, 256, 0, stream>>>(kmap_w, kfc_w, WkP, 96, 500, 64);
  biasfold_kernel<<<1, 256, 0, stream>>>(kmap_b, kfc_w, kfc_b, bkP, 500, 64);
  smallmm_kernel<<<3, 256, 0, stream>>>(kmu_w, kdec_w, WdP, 64, 32, 9);
  biasfold_kernel<<<1, 256, 0, stream>>>(kmu_b, kdec_w, kdec_b, bdP, 32, 9);
  // h64 = relu(xf @ Wk' + bk')  [25088,64]
  gemm_kernel<<<dim3(392, 1), 256, 0, stream>>>(
      xf, nullptr, 96, 96, nullptr, nullptr, WkP, 64, 0, bkP, nullptr,
      h64buf, NODES, 64, 1, 0);
  argmax9_kernel<<<98, 256, 0, stream>>>(h64buf, WdP, bdP, kint, rs);

  // ---- kNN: MFMA filter + exact fp32 rescore (h64buf dead; pk_i reuses region) ----
  knn_mfma_kernel<<<dim3(49, 8, MSPLIT), 256, 0, stream>>>(xh, xl, sqb, pk_i);
  rescore_kernel<<<6272, 256, 0, stream>>>(xf, sqb, pk_i, nn);

  // ---- output fold: W1' = io_w@up_top, W2' = fc_w@up_bot, b' ----
  smallmm_kernel<<<72, 256, 0, stream>>>(io_w, up_w, WPf, 96, 192, 192);
  smallmm_kernel<<<72, 256, 0, stream>>>(fc_w, up_w + 192 * 192, WPf + 96 * 192, 96, 192, 192);
  finalbias_kernel<<<1, 192, 0, stream>>>(io_b, fc_b, up_w, up_b, bPf);

  // ---- EdgeConv layer 1: h1 = relu(k*xi@(W1-W2) + S@W2 + k*b) ----
  gather_kernel<<<2352, 256, 0, stream>>>(xf, nn, kint, bufS);
  gemm_kernel<<<dim3(392, 2), 256, 0, stream>>>(
      xf, bufS, 96, 192, rs, nullptr, ec1_w, 96, 1, ec1_b, rs, bufH1, NODES, 96, 1, 0);

  // ---- EdgeConv layer 2 (no relu); bufH2 in region (pk_i dead) ----
  gather_kernel<<<2352, 256, 0, stream>>>(bufH1, nn, kint, bufS);
  gemm_kernel<<<dim3(392, 2), 256, 0, stream>>>(
      bufH1, bufS, 96, 192, rs, nullptr, ec2_w, 96, 1, ec2_b, rs, bufH2, NODES, 96, 0, 0);

  // ---- final (folded): relu(xf@W1' + h2@W2' + b'), transpose-store ----
  gemm_kernel<<<dim3(392, 3), 256, 0, stream>>>(
      xf, bufH2, 96, 192, nullptr, nullptr, WPf, 192, 0, bPf, nullptr,
      (float*)d_out, NODES, COUT, 1, 1);
}

// Round 11
// 623.212 us; speedup vs baseline: 1.3276x; 1.3276x over previous
//
#include <hip/hip_runtime.h>

#define NODES 25088
#define NB 8
#define NPB 3136   // nodes per batch (56*56)
#define C 96
#define KNN 9
#define COUT 192
#define MSPLIT 4   // m-range quarters for knn filter
#define T12 12     // filter depth per quarter (>= 10 guarantees exact top-9 coverage)
#define NCAND (MSPLIT * T12)  // 48 rescore candidates per query

typedef float f32x4 __attribute__((ext_vector_type(4)));
typedef float f32x16 __attribute__((ext_vector_type(16)));
typedef short s16x8 __attribute__((ext_vector_type(8)));

__device__ __forceinline__ unsigned short f2bf(float x) {
  unsigned u = __float_as_uint(x);
  return (unsigned short)((u + 0x7fffu + ((u >> 16) & 1u)) >> 16);
}
__device__ __forceinline__ float bf2f(unsigned short h) {
  return __uint_as_float(((unsigned)h) << 16);
}

// ---------------- transpose x [B,C,N] -> xf [B*N, C] ----------------
__global__ void transpose_kernel(const float* __restrict__ x, float* __restrict__ xf) {
  __shared__ float t[32][33];
  int b = blockIdx.z, ct = blockIdx.y, nt = blockIdx.x;
  int tx = threadIdx.x, ty = threadIdx.y;
  int n0 = nt * 32, c0 = ct * 32;
  const float* xb = x + (size_t)b * C * NPB;
#pragma unroll
  for (int i = 0; i < 4; i++) {
    int c = c0 + ty + i * 8;
    t[ty + i * 8][tx] = xb[(size_t)c * NPB + n0 + tx];
  }
  __syncthreads();
  float* xfb = xf + (size_t)b * NPB * C;
#pragma unroll
  for (int i = 0; i < 4; i++) {
    int n = n0 + ty + i * 8;
    xfb[(size_t)n * C + c0 + tx] = t[tx][ty + i * 8];
  }
}

// ---------------- per-node squared norm ----------------
__global__ void sq_kernel(const float* __restrict__ xf, float* __restrict__ sq) {
  int node = blockIdx.x * 256 + threadIdx.x;
  const float4* r = (const float4*)(xf + (size_t)node * C);
  float s = 0.f;
#pragma unroll
  for (int i = 0; i < 24; i++) {
    float4 v = r[i];
    s += v.x * v.x + v.y * v.y + v.z * v.z + v.w * v.w;
  }
  sq[node] = s;
}

// ---------------- fp32 -> bf16 hi/lo split ----------------
__global__ void split_kernel(const float* __restrict__ xf,
                             unsigned short* __restrict__ xh,
                             unsigned short* __restrict__ xl) {
  int i = blockIdx.x * 256 + threadIdx.x;  // one float4 per thread
  float4 v = ((const float4*)xf)[i];
  ushort4 h, l;
  h.x = f2bf(v.x); l.x = f2bf(v.x - bf2f(h.x));
  h.y = f2bf(v.y); l.y = f2bf(v.y - bf2f(h.y));
  h.z = f2bf(v.z); l.z = f2bf(v.z - bf2f(h.z));
  h.w = f2bf(v.w); l.w = f2bf(v.w - bf2f(h.w));
  ((ushort4*)xh)[i] = h;
  ((ushort4*)xl)[i] = l;
}

// ---------------- K-parallel weight fold: C[M,N] = A[M,K]@B[K,N] (+addv[n]) ----
// grid (M, ceil(N/64)), block 256 = 64 cols x 4 k-slices. A reads are
// wave-uniform scalars, B reads 64-wide coalesced, 4-way LDS reduce.
// (R10's one-thread-per-output smallmm was latency-bound: 168 us @ 1% occ.)
__global__ void foldmm_kernel(const float* __restrict__ A, const float* __restrict__ B,
                              const float* __restrict__ addv, float* __restrict__ Cc,
                              int K, int N) {
  __shared__ float sh[4][64];
  int tx = threadIdx.x & 63, ty = threadIdx.x >> 6;
  int m = blockIdx.x;
  int n = blockIdx.y * 64 + tx;
  float acc = 0.f;
  if (n < N) {
    for (int k = ty; k < K; k += 4) acc += A[m * K + k] * B[(size_t)k * N + n];
  }
  sh[ty][tx] = acc;
  __syncthreads();
  if (ty == 0 && n < N) {
    float v = sh[0][tx] + sh[1][tx] + sh[2][tx] + sh[3][tx];
    if (addv) v += addv[n];
    Cc[(size_t)m * N + n] = v;
  }
}

// bP[n] = sum_k io_b[k]*up_w[k,n] + sum_k fc_b[k]*up_w[192+k,n] + up_b[n]
__global__ void finalbias_kernel(const float* __restrict__ io_b, const float* __restrict__ fc_b,
                                 const float* __restrict__ up_w, const float* __restrict__ up_b,
                                 float* __restrict__ outb) {
  int n = threadIdx.x;  // 192
  float acc = up_b[n];
  for (int k = 0; k < 192; k++) {
    acc += io_b[k] * up_w[k * 192 + n];
    acc += fc_b[k] * up_w[(192 + k) * 192 + n];
  }
  outb[n] = acc;
}

// ---------------- logits = h64 @ WdP + bdP; kint = argmax (first max) ----------------
__global__ void argmax9_kernel(const float* __restrict__ h64, const float* __restrict__ WdP,
                               const float* __restrict__ bdP, int* __restrict__ kint,
                               float* __restrict__ rs) {
  __shared__ float wd[64 * 9];
  __shared__ float bd[9];
  int tid = threadIdx.x;
  for (int f = tid; f < 576; f += 256) wd[f] = WdP[f];
  if (tid < 9) bd[tid] = bdP[tid];
  __syncthreads();
  int node = blockIdx.x * 256 + tid;
  const float4* hp = (const float4*)(h64 + (size_t)node * 64);
  float4 h[16];
#pragma unroll
  for (int i = 0; i < 16; i++) h[i] = hp[i];
  float best = -3.4e38f;
  int bi = 0;
#pragma unroll
  for (int n = 0; n < 9; n++) {
    float acc = bd[n];
#pragma unroll
    for (int k = 0; k < 16; k++) {
      float4 hv = h[k];
      acc += hv.x * wd[(4 * k + 0) * 9 + n] + hv.y * wd[(4 * k + 1) * 9 + n] +
             hv.z * wd[(4 * k + 2) * 9 + n] + hv.w * wd[(4 * k + 3) * 9 + n];
    }
    if (acc > best) { best = acc; bi = n; }
  }
  kint[node] = bi;
  rs[node] = (float)bi;
}

// ---------------- MFMA kNN filter: approx top-12 per m-quarter per query ----------------
__global__ __launch_bounds__(256) void knn_mfma_kernel(
    const unsigned short* __restrict__ xh, const unsigned short* __restrict__ xl,
    const float* __restrict__ sq, int* __restrict__ pk_i) {
  __shared__ unsigned short mh[64 * 104];   // 13312 B (bf16-hi m-tile)
  __shared__ float ST[64 * 68];             // 17408 B (S transposed: [m][q])
  __shared__ float sqs[64];
  int tid = threadIdx.x;
  int lane = tid & 63, wv = tid >> 6;
  int b = blockIdx.y, z = blockIdx.z;
  int q0 = blockIdx.x * 64;
  int bbase = b * NPB;
  int t0 = (z * 49) / MSPLIT, t1 = ((z + 1) * 49) / MSPLIT;

  int koff = (lane >> 5) * 8;
  int rowA = bbase + q0 + (wv >> 1) * 32 + (lane & 31);
  s16x8 ah[6], al[6];
  {
    const unsigned short* ph = xh + (size_t)rowA * 96 + koff;
    const unsigned short* pl = xl + (size_t)rowA * 96 + koff;
#pragma unroll
    for (int kc = 0; kc < 6; kc++) {
      ah[kc] = *(const s16x8*)(ph + kc * 16);
      al[kc] = *(const s16x8*)(pl + kc * 16);
    }
  }
  float sqr = sq[bbase + q0 + lane];  // scan role: lane = query

  float fd[T12];
#pragma unroll
  for (int k = 0; k < T12; k++) fd[k] = 3.4e38f;

  int srow = tid >> 2, sseg = tid & 3;

  for (int t = t0; t < t1; t++) {
    int m0 = t * 64;
    __syncthreads();
    {
      const unsigned short* gh = xh + (size_t)(bbase + m0 + srow) * 96;
#pragma unroll
      for (int i = 0; i < 3; i++) {
        int s = sseg * 3 + i;
        *(s16x8*)(mh + srow * 104 + s * 8) = *(const s16x8*)(gh + s * 8);
      }
      if (tid < 64) sqs[tid] = sq[bbase + m0 + tid];
    }
    __syncthreads();

    int mrow = (wv & 1) * 32 + (lane & 31);
    s16x8 bh[6];
#pragma unroll
    for (int kc = 0; kc < 6; kc++)
      bh[kc] = *(const s16x8*)(mh + mrow * 104 + kc * 16 + koff);

    f32x16 acc = (f32x16){0.f, 0.f, 0.f, 0.f, 0.f, 0.f, 0.f, 0.f,
                          0.f, 0.f, 0.f, 0.f, 0.f, 0.f, 0.f, 0.f};
    asm volatile(
        "s_nop 1\n\t"
        "v_mfma_f32_32x32x16_bf16 %0, %1, %13, %0\n\t"
        "v_mfma_f32_32x32x16_bf16 %0, %7, %13, %0\n\t"
        "v_mfma_f32_32x32x16_bf16 %0, %2, %14, %0\n\t"
        "v_mfma_f32_32x32x16_bf16 %0, %8, %14, %0\n\t"
        "v_mfma_f32_32x32x16_bf16 %0, %3, %15, %0\n\t"
        "v_mfma_f32_32x32x16_bf16 %0, %9, %15, %0\n\t"
        "v_mfma_f32_32x32x16_bf16 %0, %4, %16, %0\n\t"
        "v_mfma_f32_32x32x16_bf16 %0, %10, %16, %0\n\t"
        "v_mfma_f32_32x32x16_bf16 %0, %5, %17, %0\n\t"
        "v_mfma_f32_32x32x16_bf16 %0, %11, %17, %0\n\t"
        "v_mfma_f32_32x32x16_bf16 %0, %6, %18, %0\n\t"
        "v_mfma_f32_32x32x16_bf16 %0, %12, %18, %0\n\t"
        "s_nop 7\n\t"
        "s_nop 7\n\t"
        "s_nop 7"
        : "+v"(acc)
        : "v"(ah[0]), "v"(ah[1]), "v"(ah[2]), "v"(ah[3]), "v"(ah[4]), "v"(ah[5]),
          "v"(al[0]), "v"(al[1]), "v"(al[2]), "v"(al[3]), "v"(al[4]), "v"(al[5]),
          "v"(bh[0]), "v"(bh[1]), "v"(bh[2]), "v"(bh[3]), "v"(bh[4]), "v"(bh[5]));

    {
      int mcol = (wv & 1) * 32 + (lane & 31);
      int qbase = (wv >> 1) * 32 + 4 * (lane >> 5);
#pragma unroll
      for (int g = 0; g < 4; g++) {
        f32x4 v = (f32x4){acc[4 * g + 0], acc[4 * g + 1], acc[4 * g + 2], acc[4 * g + 3]};
        *(f32x4*)(ST + mcol * 68 + qbase + 8 * g) = v;
      }
    }
    __syncthreads();

    int lbase = (t - t0) * 64;
#pragma unroll
    for (int i = 0; i < 16; i++) {
      int mloc = wv * 16 + i;
      float d = fmaf(-2.f, ST[mloc * 68 + lane], sqr + sqs[mloc]);
      unsigned u = (__float_as_uint(d) & 0xFFFFFC00u) | (unsigned)(lbase + mloc);
      float key = __uint_as_float(u);
      if (key < fd[T12 - 1]) {
        float t2 = key;
#pragma unroll
        for (int k = 0; k < T12; k++) {
          float lo = fminf(fd[k], t2);
          t2 = fmaxf(fd[k], t2);
          fd[k] = lo;
        }
      }
    }
  }

  __syncthreads();
  float* cd = (float*)mh;
#pragma unroll
  for (int k = 0; k < T12; k++) cd[(wv * 64 + lane) * T12 + k] = fd[k];
  __syncthreads();
  if (wv == 0) {
    float gd[T12];
#pragma unroll
    for (int k = 0; k < T12; k++) gd[k] = 3.4e38f;
    for (int s = 0; s < 4; s++) {
#pragma unroll
      for (int k = 0; k < T12; k++) {
        float key = cd[(s * 64 + lane) * T12 + k];
        if (key < gd[T12 - 1]) {
          float t2 = key;
#pragma unroll
          for (int kk = 0; kk < T12; kk++) {
            float lo = fminf(gd[kk], t2);
            t2 = fmaxf(gd[kk], t2);
            gd[kk] = lo;
          }
        }
      }
    }
    size_t base = ((size_t)(bbase + q0 + lane) * MSPLIT + z) * T12;
#pragma unroll
    for (int k = 0; k < T12; k++) {
      int mloc = (int)(__float_as_uint(gd[k]) & 0x3FFu) + t0 * 64;
      pk_i[base + k] = bbase + mloc;
    }
  }
}

// ---------------- exact fp32 rescore of NCAND candidates -> top-9 ----------------
__global__ void rescore_kernel(const float* __restrict__ xf, const float* __restrict__ sq,
                               const int* __restrict__ pk_i, int* __restrict__ nn) {
  __shared__ float qr[4][96];
  __shared__ float sqq[4];
  __shared__ float dd[4][NCAND];
  __shared__ int jj[4][NCAND];
  int tid = threadIdx.x;
  int qloc = tid >> 6, c = tid & 63;
  int qbase = blockIdx.x * 4;
  for (int f = tid; f < 4 * 96; f += 256)
    qr[f / 96][f % 96] = xf[(size_t)(qbase + f / 96) * 96 + f % 96];
  if (tid < 4) sqq[tid] = sq[qbase + tid];
  __syncthreads();
  if (c < NCAND) {
    int q = qbase + qloc;
    int j = pk_i[(size_t)q * NCAND + c];
    const float4* qp = (const float4*)qr[qloc];
    const float4* mp = (const float4*)(xf + (size_t)j * 96);
    float d0 = 0.f, d1 = 0.f, d2 = 0.f, d3 = 0.f;
#pragma unroll
    for (int i = 0; i < 24; i++) {
      float4 qv = qp[i];
      float4 mv = mp[i];
      d0 += qv.x * mv.x;
      d1 += qv.y * mv.y;
      d2 += qv.z * mv.z;
      d3 += qv.w * mv.w;
    }
    dd[qloc][c] = (sqq[qloc] - 2.0f * ((d0 + d1) + (d2 + d3))) + sq[j];
    jj[qloc][c] = j;
  }
  __syncthreads();
  if (c == 0) {
    int q = qbase + qloc;
    float fd[KNN];
    int fi[KNN];
#pragma unroll
    for (int k = 0; k < KNN; k++) { fd[k] = 3.4e38f; fi[k] = 0x7fffffff; }
    for (int e = 0; e < NCAND; e++) {
      float d = dd[qloc][e];
      int j = jj[qloc][e];
      if (d < fd[KNN - 1] || (d == fd[KNN - 1] && j < fi[KNN - 1])) {
        fd[KNN - 1] = d;
        fi[KNN - 1] = j;
#pragma unroll
        for (int k = KNN - 1; k > 0; --k) {
          bool sw = (fd[k] < fd[k - 1]) || (fd[k] == fd[k - 1] && fi[k] < fi[k - 1]);
          if (sw) {
            float td = fd[k]; fd[k] = fd[k - 1]; fd[k - 1] = td;
            int ti = fi[k]; fi[k] = fi[k - 1]; fi[k - 1] = ti;
          }
        }
      }
    }
#pragma unroll
    for (int k = 0; k < KNN; k++) nn[(size_t)q * KNN + k] = fi[k];
  }
}

// ---------------- gather-sum of kept neighbors ----------------
__global__ void gather_kernel(const float* __restrict__ feat, const int* __restrict__ nn,
                              const int* __restrict__ kint, float* __restrict__ out) {
  int idx = blockIdx.x * 256 + threadIdx.x;
  int node = idx / 24, c4 = idx % 24;
  int kc = kint[node];
  const int* nr = nn + (size_t)node * KNN;
  float4 acc = make_float4(0.f, 0.f, 0.f, 0.f);
  for (int k = 0; k < kc; k++) {
    int j = nr[k];
    float4 v = ((const float4*)(feat + (size_t)j * C))[c4];
    acc.x += v.x; acc.y += v.y; acc.z += v.z; acc.w += v.w;
  }
  ((float4*)(out + (size_t)node * C))[c4] = acc;
}

// ---------------- generic fp32 GEMM ----------------
__global__ __launch_bounds__(256) void gemm_kernel(
    const float* __restrict__ A0, const float* __restrict__ A1, int K0, int Ktot,
    const float* __restrict__ sc0, const float* __restrict__ sc1,
    const float* __restrict__ B, int ldb, int bmode,
    const float* __restrict__ bias, const float* __restrict__ bscale,
    float* __restrict__ Cc, int M, int N, int relu, int tstore) {
  __shared__ float As[16][68];
  __shared__ float Bs[16][68];
  int tid = threadIdx.x;
  int tx = tid & 15, ty = tid >> 4;
  int row0 = blockIdx.x * 64, col0 = blockIdx.y * 64;
  float acc[4][4] = {};
  int ai = tid >> 2;
  int ak = (tid & 3) * 4;
  int bk = tid >> 4;
  int bj = (tid & 15) * 4;
  bool edge = (col0 + 64 > N);

  for (int k0 = 0; k0 < Ktot; k0 += 16) {
    {
      const float* Ap;
      const float* sc;
      int lda, kk;
      if (k0 < K0) { Ap = A0; lda = K0; sc = sc0; kk = k0; }
      else { Ap = A1; lda = Ktot - K0; sc = sc1; kk = k0 - K0; }
      int r = row0 + ai;
      float4 v = *(const float4*)(Ap + (size_t)r * lda + kk + ak);
      if (sc) { float s = sc[r]; v.x *= s; v.y *= s; v.z *= s; v.w *= s; }
      As[ak + 0][ai] = v.x;
      As[ak + 1][ai] = v.y;
      As[ak + 2][ai] = v.z;
      As[ak + 3][ai] = v.w;
    }
    {
      int kg = k0 + bk;
      int j = col0 + bj;
      float4 v;
      if (!edge) {
        v = *(const float4*)(B + (size_t)kg * ldb + j);
        if (bmode == 1 && kg < 96) {
          float4 w = *(const float4*)(B + (size_t)(kg + 96) * ldb + j);
          v.x -= w.x; v.y -= w.y; v.z -= w.z; v.w -= w.w;
        }
      } else {
        float tmp[4];
#pragma unroll
        for (int e = 0; e < 4; e++) {
          int jjx = j + e;
          float val = 0.f;
          if (jjx < N) {
            val = B[(size_t)kg * ldb + jjx];
            if (bmode == 1 && kg < 96) val -= B[(size_t)(kg + 96) * ldb + jjx];
          }
          tmp[e] = val;
        }
        v = make_float4(tmp[0], tmp[1], tmp[2], tmp[3]);
      }
      *(float4*)&Bs[bk][bj] = v;
    }
    __syncthreads();
#pragma unroll
    for (int kk = 0; kk < 16; kk++) {
      float4 av = *(const float4*)&As[kk][ty * 4];
      float4 bv = *(const float4*)&Bs[kk][tx * 4];
      acc[0][0] += av.x * bv.x; acc[0][1] += av.x * bv.y; acc[0][2] += av.x * bv.z; acc[0][3] += av.x * bv.w;
      acc[1][0] += av.y * bv.x; acc[1][1] += av.y * bv.y; acc[1][2] += av.y * bv.z; acc[1][3] += av.y * bv.w;
      acc[2][0] += av.z * bv.x; acc[2][1] += av.z * bv.y; acc[2][2] += av.z * bv.z; acc[2][3] += av.z * bv.w;
      acc[3][0] += av.w * bv.x; acc[3][1] += av.w * bv.y; acc[3][2] += av.w * bv.z; acc[3][3] += av.w * bv.w;
    }
    __syncthreads();
  }
#pragma unroll
  for (int ii = 0; ii < 4; ii++) {
    int r = row0 + ty * 4 + ii;
    float bsv = bscale ? bscale[r] : 1.f;
#pragma unroll
    for (int jjx = 0; jjx < 4; jjx++) {
      int j = col0 + tx * 4 + jjx;
      if (edge && j >= N) continue;
      float v = acc[ii][jjx];
      if (bias) v += bsv * bias[j];
      if (relu) v = fmaxf(v, 0.f);
      if (tstore) {
        int bb = r / NPB, n = r % NPB;
        Cc[(size_t)bb * COUT * NPB + (size_t)j * NPB + n] = v;
      } else {
        Cc[(size_t)r * N + j] = v;
      }
    }
  }
}

extern "C" void kernel_launch(void* const* d_in, const int* in_sizes, int n_in,
                              void* d_out, int out_size, void* d_ws, size_t ws_size,
                              hipStream_t stream) {
  const float* x      = (const float*)d_in[0];
  const float* kmap_w = (const float*)d_in[1];
  const float* kmap_b = (const float*)d_in[2];
  const float* kfc_w  = (const float*)d_in[3];
  const float* kfc_b  = (const float*)d_in[4];
  const float* kmu_w  = (const float*)d_in[5];
  const float* kmu_b  = (const float*)d_in[6];
  const float* kdec_w = (const float*)d_in[7];
  const float* kdec_b = (const float*)d_in[8];
  const float* ec1_w  = (const float*)d_in[9];
  const float* ec1_b  = (const float*)d_in[10];
  const float* ec2_w  = (const float*)d_in[11];
  const float* ec2_b  = (const float*)d_in[12];
  const float* fc_w   = (const float*)d_in[13];
  const float* fc_b   = (const float*)d_in[14];
  const float* io_w   = (const float*)d_in[15];
  const float* io_b   = (const float*)d_in[16];
  const float* up_w   = (const float*)d_in[17];
  const float* up_b   = (const float*)d_in[18];

  // ---- workspace layout (liveness-aliased) ----
  char* ws = (char*)d_ws;
  size_t off = 0;
  auto alloc = [&](size_t bytes) -> void* {
    void* p = ws + off;
    off += (bytes + 255) & ~(size_t)255;
    return p;
  };
  float* xf    = (float*)alloc((size_t)NODES * C * 4);   // live until final GEMM
  float* sqb   = (float*)alloc((size_t)NODES * 4);
  float* rs    = (float*)alloc((size_t)NODES * 4);
  int*   kint  = (int*)alloc((size_t)NODES * 4);
  int*   nn    = (int*)alloc((size_t)NODES * KNN * 4);
  float* bufH1 = (float*)alloc((size_t)NODES * C * 4);
  float* bufS  = (float*)alloc((size_t)NODES * C * 4);
  char*  region = (char*)alloc((size_t)NODES * COUT * 4);  // 19.27 MB shared region
  // region timeline: h64buf (6.4MB) -> pk_i (4.8MB) -> bufH2 (9.6MB); all serial.
  float* h64buf = (float*)region;
  int*   pk_i   = (int*)region;
  float* bufH2  = (float*)region;
  // fold weights at region+12MB (176KB; never overlaps the above)
  char* wbase = region + 12 * 1024 * 1024;
  float* WkP = (float*)wbase;                  // [96,64]
  float* bkP = WkP + 96 * 64;                  // [64]
  float* WdP = bkP + 64;                       // [64,9]
  float* bdP = WdP + 64 * 9;                   // [9]
  float* WPf = bdP + 16;                       // [192,192] (rows 0-95 = W1', 96-191 = W2')
  float* bPf = WPf + 192 * 192;                // [192]
  unsigned short* xh = (unsigned short*)bufH1;  // bf16 hi; dead after knn
  unsigned short* xl = (unsigned short*)bufS;   // bf16 lo; dead after knn

  transpose_kernel<<<dim3(98, 3, 8), dim3(32, 8), 0, stream>>>(x, xf);
  sq_kernel<<<98, 256, 0, stream>>>(xf, sqb);
  split_kernel<<<2352, 256, 0, stream>>>(xf, xh, xl);

  // ---- VAE fold: Wk' = kmap_w@kfc_w, Wd' = kmu_w@kdec_w (+bias folds) ----
  foldmm_kernel<<<dim3(96, 1), 256, 0, stream>>>(kmap_w, kfc_w, nullptr, WkP, 500, 64);
  foldmm_kernel<<<dim3(1, 1), 256, 0, stream>>>(kmap_b, kfc_w, kfc_b, bkP, 500, 64);
  foldmm_kernel<<<dim3(64, 1), 256, 0, stream>>>(kmu_w, kdec_w, nullptr, WdP, 32, 9);
  foldmm_kernel<<<dim3(1, 1), 256, 0, stream>>>(kmu_b, kdec_w, kdec_b, bdP, 32, 9);
  // h64 = relu(xf @ Wk' + bk')  [25088,64]
  gemm_kernel<<<dim3(392, 1), 256, 0, stream>>>(
      xf, nullptr, 96, 96, nullptr, nullptr, WkP, 64, 0, bkP, nullptr,
      h64buf, NODES, 64, 1, 0);
  argmax9_kernel<<<98, 256, 0, stream>>>(h64buf, WdP, bdP, kint, rs);

  // ---- kNN: MFMA filter + exact fp32 rescore (h64buf dead; pk_i reuses region) ----
  knn_mfma_kernel<<<dim3(49, 8, MSPLIT), 256, 0, stream>>>(xh, xl, sqb, pk_i);
  rescore_kernel<<<6272, 256, 0, stream>>>(xf, sqb, pk_i, nn);

  // ---- output fold: W1' = io_w@up_top, W2' = fc_w@up_bot, b' ----
  foldmm_kernel<<<dim3(96, 3), 256, 0, stream>>>(io_w, up_w, nullptr, WPf, 192, 192);
  foldmm_kernel<<<dim3(96, 3), 256, 0, stream>>>(fc_w, up_w + 192 * 192, nullptr,
                                                 WPf + 96 * 192, 192, 192);
  finalbias_kernel<<<1, 192, 0, stream>>>(io_b, fc_b, up_w, up_b, bPf);

  // ---- EdgeConv layer 1: h1 = relu(k*xi@(W1-W2) + S@W2 + k*b) ----
  gather_kernel<<<2352, 256, 0, stream>>>(xf, nn, kint, bufS);
  gemm_kernel<<<dim3(392, 2), 256, 0, stream>>>(
      xf, bufS, 96, 192, rs, nullptr, ec1_w, 96, 1, ec1_b, rs, bufH1, NODES, 96, 1, 0);

  // ---- EdgeConv layer 2 (no relu); bufH2 in region (pk_i dead) ----
  gather_kernel<<<2352, 256, 0, stream>>>(bufH1, nn, kint, bufS);
  gemm_kernel<<<dim3(392, 2), 256, 0, stream>>>(
      bufH1, bufS, 96, 192, rs, nullptr, ec2_w, 96, 1, ec2_b, rs, bufH2, NODES, 96, 0, 0);

  // ---- final (folded): relu(xf@W1' + h2@W2' + b'), transpose-store ----
  gemm_kernel<<<dim3(392, 3), 256, 0, stream>>>(
      xf, bufH2, 96, 192, nullptr, nullptr, WPf, 192, 0, bPf, nullptr,
      (float*)d_out, NODES, COUT, 1, 1);
}

// Round 12
// 605.594 us; speedup vs baseline: 1.3663x; 1.0291x over previous
//
#include <hip/hip_runtime.h>

#define NODES 25088
#define NB 8
#define NPB 3136   // nodes per batch (56*56)
#define C 96
#define KNN 9
#define COUT 192
#define MSPLIT 4   // m-range quarters for knn filter
#define T12 12     // filter depth per quarter
#define NCAND (MSPLIT * T12)  // 48 rescore candidates per query

typedef float f32x4 __attribute__((ext_vector_type(4)));
typedef float f32x16 __attribute__((ext_vector_type(16)));
typedef short s16x8 __attribute__((ext_vector_type(8)));

__device__ __forceinline__ unsigned short f2bf(float x) {
  unsigned u = __float_as_uint(x);
  return (unsigned short)((u + 0x7fffu + ((u >> 16) & 1u)) >> 16);
}
__device__ __forceinline__ float bf2f(unsigned short h) {
  return __uint_as_float(((unsigned)h) << 16);
}

// ---------------- transpose x [B,C,N] -> xf [B*N, C] ----------------
__global__ void transpose_kernel(const float* __restrict__ x, float* __restrict__ xf) {
  __shared__ float t[32][33];
  int b = blockIdx.z, ct = blockIdx.y, nt = blockIdx.x;
  int tx = threadIdx.x, ty = threadIdx.y;
  int n0 = nt * 32, c0 = ct * 32;
  const float* xb = x + (size_t)b * C * NPB;
#pragma unroll
  for (int i = 0; i < 4; i++) {
    int c = c0 + ty + i * 8;
    t[ty + i * 8][tx] = xb[(size_t)c * NPB + n0 + tx];
  }
  __syncthreads();
  float* xfb = xf + (size_t)b * NPB * C;
#pragma unroll
  for (int i = 0; i < 4; i++) {
    int n = n0 + ty + i * 8;
    xfb[(size_t)n * C + c0 + tx] = t[tx][ty + i * 8];
  }
}

// ---------------- fused per-node sq-norm + bf16 hi/lo split ----------------
__global__ void sqsplit_kernel(const float* __restrict__ xf, float* __restrict__ sq,
                               unsigned short* __restrict__ xh,
                               unsigned short* __restrict__ xl) {
  int node = blockIdx.x * 256 + threadIdx.x;
  const float4* r = (const float4*)(xf + (size_t)node * C);
  ushort4* hp = (ushort4*)(xh + (size_t)node * C);
  ushort4* lp = (ushort4*)(xl + (size_t)node * C);
  float s = 0.f;
#pragma unroll
  for (int i = 0; i < 24; i++) {
    float4 v = r[i];
    s += v.x * v.x + v.y * v.y + v.z * v.z + v.w * v.w;
    ushort4 h, l;
    h.x = f2bf(v.x); l.x = f2bf(v.x - bf2f(h.x));
    h.y = f2bf(v.y); l.y = f2bf(v.y - bf2f(h.y));
    h.z = f2bf(v.z); l.z = f2bf(v.z - bf2f(h.z));
    h.w = f2bf(v.w); l.w = f2bf(v.w - bf2f(h.w));
    hp[i] = h;
    lp[i] = l;
  }
  sq[node] = s;
}

// ---------------- K-parallel weight fold (fp32): C[M,N] = A@B (+addv) ----------------
__global__ void foldmm_kernel(const float* __restrict__ A, const float* __restrict__ B,
                              const float* __restrict__ addv, float* __restrict__ Cc,
                              int K, int N) {
  __shared__ float sh[4][64];
  int tx = threadIdx.x & 63, ty = threadIdx.x >> 6;
  int m = blockIdx.x;
  int n = blockIdx.y * 64 + tx;
  float acc = 0.f;
  if (n < N) {
    for (int k = ty; k < K; k += 4) acc += A[m * K + k] * B[(size_t)k * N + n];
  }
  sh[ty][tx] = acc;
  __syncthreads();
  if (ty == 0 && n < N) {
    float v = sh[0][tx] + sh[1][tx] + sh[2][tx] + sh[3][tx];
    if (addv) v += addv[n];
    Cc[(size_t)m * N + n] = v;
  }
}

// ---------------- EdgeConv B-transform -> bf16 hi/lo, stored [N=96][K=192] ----------------
__global__ void fold_ec_bt(const float* __restrict__ ec_w, unsigned short* __restrict__ Bth,
                           unsigned short* __restrict__ Btl) {
  int t = blockIdx.x * 256 + threadIdx.x;
  if (t >= 96 * 192) return;
  int n = t / 192, k = t % 192;
  float v = ec_w[(size_t)k * 96 + n];
  if (k < 96) v -= ec_w[(size_t)(k + 96) * 96 + n];
  unsigned short h = f2bf(v);
  Bth[t] = h;
  Btl[t] = f2bf(v - bf2f(h));
}

// ---------------- final folded weights fp32 [192,192] -> bf16 pair [N=192][K=192] ----------------
__global__ void fold_f_bt(const float* __restrict__ W, unsigned short* __restrict__ Bth,
                          unsigned short* __restrict__ Btl) {
  int t = blockIdx.x * 256 + threadIdx.x;
  if (t >= 192 * 192) return;
  int n = t / 192, k = t % 192;
  float v = W[(size_t)k * 192 + n];
  unsigned short h = f2bf(v);
  Bth[t] = h;
  Btl[t] = f2bf(v - bf2f(h));
}

// bP[n] = sum_k io_b[k]*up_w[k,n] + sum_k fc_b[k]*up_w[192+k,n] + up_b[n]
__global__ void finalbias_kernel(const float* __restrict__ io_b, const float* __restrict__ fc_b,
                                 const float* __restrict__ up_w, const float* __restrict__ up_b,
                                 float* __restrict__ outb) {
  int n = threadIdx.x;  // 192
  float acc = up_b[n];
  for (int k = 0; k < 192; k++) {
    acc += io_b[k] * up_w[k * 192 + n];
    acc += fc_b[k] * up_w[(192 + k) * 192 + n];
  }
  outb[n] = acc;
}

// ---------------- logits = h64 @ WdP + bdP; kint = argmax (first max) ----------------
__global__ void argmax9_kernel(const float* __restrict__ h64, const float* __restrict__ WdP,
                               const float* __restrict__ bdP, int* __restrict__ kint,
                               float* __restrict__ rs) {
  __shared__ float wd[64 * 9];
  __shared__ float bd[9];
  int tid = threadIdx.x;
  for (int f = tid; f < 576; f += 256) wd[f] = WdP[f];
  if (tid < 9) bd[tid] = bdP[tid];
  __syncthreads();
  int node = blockIdx.x * 256 + tid;
  const float4* hp = (const float4*)(h64 + (size_t)node * 64);
  float4 h[16];
#pragma unroll
  for (int i = 0; i < 16; i++) h[i] = hp[i];
  float best = -3.4e38f;
  int bi = 0;
#pragma unroll
  for (int n = 0; n < 9; n++) {
    float acc = bd[n];
#pragma unroll
    for (int k = 0; k < 16; k++) {
      float4 hv = h[k];
      acc += hv.x * wd[(4 * k + 0) * 9 + n] + hv.y * wd[(4 * k + 1) * 9 + n] +
             hv.z * wd[(4 * k + 2) * 9 + n] + hv.w * wd[(4 * k + 3) * 9 + n];
    }
    if (acc > best) { best = acc; bi = n; }
  }
  kint[node] = bi;
  rs[node] = (float)bi;
}

// ---------------- MFMA kNN filter (unchanged from R9/R11 verified) ----------------
__global__ __launch_bounds__(256) void knn_mfma_kernel(
    const unsigned short* __restrict__ xh, const unsigned short* __restrict__ xl,
    const float* __restrict__ sq, int* __restrict__ pk_i) {
  __shared__ unsigned short mh[64 * 104];
  __shared__ float ST[64 * 68];
  __shared__ float sqs[64];
  int tid = threadIdx.x;
  int lane = tid & 63, wv = tid >> 6;
  int b = blockIdx.y, z = blockIdx.z;
  int q0 = blockIdx.x * 64;
  int bbase = b * NPB;
  int t0 = (z * 49) / MSPLIT, t1 = ((z + 1) * 49) / MSPLIT;

  int koff = (lane >> 5) * 8;
  int rowA = bbase + q0 + (wv >> 1) * 32 + (lane & 31);
  s16x8 ah[6], al[6];
  {
    const unsigned short* ph = xh + (size_t)rowA * 96 + koff;
    const unsigned short* pl = xl + (size_t)rowA * 96 + koff;
#pragma unroll
    for (int kc = 0; kc < 6; kc++) {
      ah[kc] = *(const s16x8*)(ph + kc * 16);
      al[kc] = *(const s16x8*)(pl + kc * 16);
    }
  }
  float sqr = sq[bbase + q0 + lane];

  float fd[T12];
#pragma unroll
  for (int k = 0; k < T12; k++) fd[k] = 3.4e38f;

  int srow = tid >> 2, sseg = tid & 3;

  for (int t = t0; t < t1; t++) {
    int m0 = t * 64;
    __syncthreads();
    {
      const unsigned short* gh = xh + (size_t)(bbase + m0 + srow) * 96;
#pragma unroll
      for (int i = 0; i < 3; i++) {
        int s = sseg * 3 + i;
        *(s16x8*)(mh + srow * 104 + s * 8) = *(const s16x8*)(gh + s * 8);
      }
      if (tid < 64) sqs[tid] = sq[bbase + m0 + tid];
    }
    __syncthreads();

    int mrow = (wv & 1) * 32 + (lane & 31);
    s16x8 bh[6];
#pragma unroll
    for (int kc = 0; kc < 6; kc++)
      bh[kc] = *(const s16x8*)(mh + mrow * 104 + kc * 16 + koff);

    f32x16 acc = (f32x16){0.f, 0.f, 0.f, 0.f, 0.f, 0.f, 0.f, 0.f,
                          0.f, 0.f, 0.f, 0.f, 0.f, 0.f, 0.f, 0.f};
    asm volatile(
        "s_nop 1\n\t"
        "v_mfma_f32_32x32x16_bf16 %0, %1, %13, %0\n\t"
        "v_mfma_f32_32x32x16_bf16 %0, %7, %13, %0\n\t"
        "v_mfma_f32_32x32x16_bf16 %0, %2, %14, %0\n\t"
        "v_mfma_f32_32x32x16_bf16 %0, %8, %14, %0\n\t"
        "v_mfma_f32_32x32x16_bf16 %0, %3, %15, %0\n\t"
        "v_mfma_f32_32x32x16_bf16 %0, %9, %15, %0\n\t"
        "v_mfma_f32_32x32x16_bf16 %0, %4, %16, %0\n\t"
        "v_mfma_f32_32x32x16_bf16 %0, %10, %16, %0\n\t"
        "v_mfma_f32_32x32x16_bf16 %0, %5, %17, %0\n\t"
        "v_mfma_f32_32x32x16_bf16 %0, %11, %17, %0\n\t"
        "v_mfma_f32_32x32x16_bf16 %0, %6, %18, %0\n\t"
        "v_mfma_f32_32x32x16_bf16 %0, %12, %18, %0\n\t"
        "s_nop 7\n\t"
        "s_nop 7\n\t"
        "s_nop 7"
        : "+v"(acc)
        : "v"(ah[0]), "v"(ah[1]), "v"(ah[2]), "v"(ah[3]), "v"(ah[4]), "v"(ah[5]),
          "v"(al[0]), "v"(al[1]), "v"(al[2]), "v"(al[3]), "v"(al[4]), "v"(al[5]),
          "v"(bh[0]), "v"(bh[1]), "v"(bh[2]), "v"(bh[3]), "v"(bh[4]), "v"(bh[5]));

    {
      int mcol = (wv & 1) * 32 + (lane & 31);
      int qbase = (wv >> 1) * 32 + 4 * (lane >> 5);
#pragma unroll
      for (int g = 0; g < 4; g++) {
        f32x4 v = (f32x4){acc[4 * g + 0], acc[4 * g + 1], acc[4 * g + 2], acc[4 * g + 3]};
        *(f32x4*)(ST + mcol * 68 + qbase + 8 * g) = v;
      }
    }
    __syncthreads();

    int lbase = (t - t0) * 64;
#pragma unroll
    for (int i = 0; i < 16; i++) {
      int mloc = wv * 16 + i;
      float d = fmaf(-2.f, ST[mloc * 68 + lane], sqr + sqs[mloc]);
      unsigned u = (__float_as_uint(d) & 0xFFFFFC00u) | (unsigned)(lbase + mloc);
      float key = __uint_as_float(u);
      if (key < fd[T12 - 1]) {
        float t2 = key;
#pragma unroll
        for (int k = 0; k < T12; k++) {
          float lo = fminf(fd[k], t2);
          t2 = fmaxf(fd[k], t2);
          fd[k] = lo;
        }
      }
    }
  }

  __syncthreads();
  float* cd = (float*)mh;
#pragma unroll
  for (int k = 0; k < T12; k++) cd[(wv * 64 + lane) * T12 + k] = fd[k];
  __syncthreads();
  if (wv == 0) {
    float gd[T12];
#pragma unroll
    for (int k = 0; k < T12; k++) gd[k] = 3.4e38f;
    for (int s = 0; s < 4; s++) {
#pragma unroll
      for (int k = 0; k < T12; k++) {
        float key = cd[(s * 64 + lane) * T12 + k];
        if (key < gd[T12 - 1]) {
          float t2 = key;
#pragma unroll
          for (int kk = 0; kk < T12; kk++) {
            float lo = fminf(gd[kk], t2);
            t2 = fmaxf(gd[kk], t2);
            gd[kk] = lo;
          }
        }
      }
    }
    size_t base = ((size_t)(bbase + q0 + lane) * MSPLIT + z) * T12;
#pragma unroll
    for (int k = 0; k < T12; k++) {
      int mloc = (int)(__float_as_uint(gd[k]) & 0x3FFu) + t0 * 64;
      pk_i[base + k] = bbase + mloc;
    }
  }
}

// ---------------- exact fp32 rescore (unchanged) ----------------
__global__ void rescore_kernel(const float* __restrict__ xf, const float* __restrict__ sq,
                               const int* __restrict__ pk_i, int* __restrict__ nn) {
  __shared__ float qr[4][96];
  __shared__ float sqq[4];
  __shared__ float dd[4][NCAND];
  __shared__ int jj[4][NCAND];
  int tid = threadIdx.x;
  int qloc = tid >> 6, c = tid & 63;
  int qbase = blockIdx.x * 4;
  for (int f = tid; f < 4 * 96; f += 256)
    qr[f / 96][f % 96] = xf[(size_t)(qbase + f / 96) * 96 + f % 96];
  if (tid < 4) sqq[tid] = sq[qbase + tid];
  __syncthreads();
  if (c < NCAND) {
    int q = qbase + qloc;
    int j = pk_i[(size_t)q * NCAND + c];
    const float4* qp = (const float4*)qr[qloc];
    const float4* mp = (const float4*)(xf + (size_t)j * 96);
    float d0 = 0.f, d1 = 0.f, d2 = 0.f, d3 = 0.f;
#pragma unroll
    for (int i = 0; i < 24; i++) {
      float4 qv = qp[i];
      float4 mv = mp[i];
      d0 += qv.x * mv.x;
      d1 += qv.y * mv.y;
      d2 += qv.z * mv.z;
      d3 += qv.w * mv.w;
    }
    dd[qloc][c] = (sqq[qloc] - 2.0f * ((d0 + d1) + (d2 + d3))) + sq[j];
    jj[qloc][c] = j;
  }
  __syncthreads();
  if (c == 0) {
    int q = qbase + qloc;
    float fd[KNN];
    int fi[KNN];
#pragma unroll
    for (int k = 0; k < KNN; k++) { fd[k] = 3.4e38f; fi[k] = 0x7fffffff; }
    for (int e = 0; e < NCAND; e++) {
      float d = dd[qloc][e];
      int j = jj[qloc][e];
      if (d < fd[KNN - 1] || (d == fd[KNN - 1] && j < fi[KNN - 1])) {
        fd[KNN - 1] = d;
        fi[KNN - 1] = j;
#pragma unroll
        for (int k = KNN - 1; k > 0; --k) {
          bool sw = (fd[k] < fd[k - 1]) || (fd[k] == fd[k - 1] && fi[k] < fi[k - 1]);
          if (sw) {
            float td = fd[k]; fd[k] = fd[k - 1]; fd[k - 1] = td;
            int ti = fi[k]; fi[k] = fi[k - 1]; fi[k - 1] = ti;
          }
        }
      }
    }
#pragma unroll
    for (int k = 0; k < KNN; k++) nn[(size_t)q * KNN + k] = fi[k];
  }
}

// ---------------- gather-sum (fp32 feat) -> bf16 hi/lo pair ----------------
__global__ void gather_f32_kernel(const float* __restrict__ feat, const int* __restrict__ nn,
                                  const int* __restrict__ kint,
                                  unsigned short* __restrict__ Sh,
                                  unsigned short* __restrict__ Sl) {
  int idx = blockIdx.x * 256 + threadIdx.x;
  int node = idx / 24, c4 = idx % 24;
  int kc = kint[node];
  const int* nr = nn + (size_t)node * KNN;
  float4 acc = make_float4(0.f, 0.f, 0.f, 0.f);
  for (int k = 0; k < kc; k++) {
    int j = nr[k];
    float4 v = ((const float4*)(feat + (size_t)j * C))[c4];
    acc.x += v.x; acc.y += v.y; acc.z += v.z; acc.w += v.w;
  }
  ushort4 h, l;
  h.x = f2bf(acc.x); l.x = f2bf(acc.x - bf2f(h.x));
  h.y = f2bf(acc.y); l.y = f2bf(acc.y - bf2f(h.y));
  h.z = f2bf(acc.z); l.z = f2bf(acc.z - bf2f(h.z));
  h.w = f2bf(acc.w); l.w = f2bf(acc.w - bf2f(h.w));
  ((ushort4*)(Sh + (size_t)node * C))[c4] = h;
  ((ushort4*)(Sl + (size_t)node * C))[c4] = l;
}

// ---------------- gather-sum (bf16-pair feat) -> bf16 hi/lo pair ----------------
__global__ void gather_bf_kernel(const unsigned short* __restrict__ fh,
                                 const unsigned short* __restrict__ fl,
                                 const int* __restrict__ nn, const int* __restrict__ kint,
                                 unsigned short* __restrict__ Sh,
                                 unsigned short* __restrict__ Sl) {
  int idx = blockIdx.x * 256 + threadIdx.x;
  int node = idx / 24, c4 = idx % 24;
  int kc = kint[node];
  const int* nr = nn + (size_t)node * KNN;
  float4 acc = make_float4(0.f, 0.f, 0.f, 0.f);
  for (int k = 0; k < kc; k++) {
    int j = nr[k];
    ushort4 h = ((const ushort4*)(fh + (size_t)j * C))[c4];
    ushort4 l = ((const ushort4*)(fl + (size_t)j * C))[c4];
    acc.x += bf2f(h.x) + bf2f(l.x);
    acc.y += bf2f(h.y) + bf2f(l.y);
    acc.z += bf2f(h.z) + bf2f(l.z);
    acc.w += bf2f(h.w) + bf2f(l.w);
  }
  ushort4 h, l;
  h.x = f2bf(acc.x); l.x = f2bf(acc.x - bf2f(h.x));
  h.y = f2bf(acc.y); l.y = f2bf(acc.y - bf2f(h.y));
  h.z = f2bf(acc.z); l.z = f2bf(acc.z - bf2f(h.z));
  h.w = f2bf(acc.w); l.w = f2bf(acc.w - bf2f(h.w));
  ((ushort4*)(Sh + (size_t)node * C))[c4] = h;
  ((ushort4*)(Sl + (size_t)node * C))[c4] = l;
}

// ---------------- MFMA EdgeConv GEMM ----------------
// out = rs .* (A0@Btop + bias) + A1@Bbot  (relu opt), out as bf16 hi/lo pair.
// A0/A1: [M,96] bf16 pairs. Bt: [96 cols][192 k] bf16 pairs (Btop=k<96, Bbot=k>=96).
// block 256 = 4 waves x 32 rows (M-tile 128); each wave: 3 col-strips of 32.
// K-loop reads A-frags and B-frags straight from global (L1/L2); no barriers.
__global__ __launch_bounds__(256) void mfma_ec_kernel(
    const unsigned short* __restrict__ A0h, const unsigned short* __restrict__ A0l,
    const unsigned short* __restrict__ A1h, const unsigned short* __restrict__ A1l,
    const unsigned short* __restrict__ Bth, const unsigned short* __restrict__ Btl,
    const float* __restrict__ rs, const float* __restrict__ bias, int relu,
    unsigned short* __restrict__ Oh, unsigned short* __restrict__ Ol) {
  __shared__ float rsL[128];
  __shared__ float bL[96];
  int tid = threadIdx.x, lane = tid & 63, wv = tid >> 6;
  int m0 = blockIdx.x * 128;
  if (tid < 128) rsL[tid] = rs[m0 + tid];
  if (tid < 96) bL[tid] = bias[tid];
  __syncthreads();

  int koff = (lane >> 5) * 8;
  int arow = m0 + wv * 32 + (lane & 31);
  const unsigned short* a0h = A0h + (size_t)arow * 96 + koff;
  const unsigned short* a0l = A0l + (size_t)arow * 96 + koff;
  const unsigned short* a1h = A1h + (size_t)arow * 96 + koff;
  const unsigned short* a1l = A1l + (size_t)arow * 96 + koff;
  int ncol = lane & 31;

  f32x16 acc1[3], acc2[3];
#pragma unroll
  for (int s = 0; s < 3; s++) {
    acc1[s] = (f32x16){0.f, 0.f, 0.f, 0.f, 0.f, 0.f, 0.f, 0.f,
                       0.f, 0.f, 0.f, 0.f, 0.f, 0.f, 0.f, 0.f};
    acc2[s] = acc1[s];
  }

#pragma unroll
  for (int c = 0; c < 6; c++) {  // k = c*16 (<96): A0 @ Btop
    s16x8 ah = *(const s16x8*)(a0h + c * 16);
    s16x8 al = *(const s16x8*)(a0l + c * 16);
#pragma unroll
    for (int s = 0; s < 3; s++) {
      size_t bo = (size_t)(s * 32 + ncol) * 192 + c * 16 + koff;
      s16x8 bh = *(const s16x8*)(Bth + bo);
      s16x8 bl = *(const s16x8*)(Btl + bo);
      acc1[s] = __builtin_amdgcn_mfma_f32_32x32x16_bf16(ah, bh, acc1[s], 0, 0, 0);
      acc1[s] = __builtin_amdgcn_mfma_f32_32x32x16_bf16(al, bh, acc1[s], 0, 0, 0);
      acc1[s] = __builtin_amdgcn_mfma_f32_32x32x16_bf16(ah, bl, acc1[s], 0, 0, 0);
    }
  }
#pragma unroll
  for (int c = 6; c < 12; c++) {  // k = c*16 (>=96): A1 @ Bbot
    s16x8 ah = *(const s16x8*)(a1h + (c - 6) * 16);
    s16x8 al = *(const s16x8*)(a1l + (c - 6) * 16);
#pragma unroll
    for (int s = 0; s < 3; s++) {
      size_t bo = (size_t)(s * 32 + ncol) * 192 + c * 16 + koff;
      s16x8 bh = *(const s16x8*)(Bth + bo);
      s16x8 bl = *(const s16x8*)(Btl + bo);
      acc2[s] = __builtin_amdgcn_mfma_f32_32x32x16_bf16(ah, bh, acc2[s], 0, 0, 0);
      acc2[s] = __builtin_amdgcn_mfma_f32_32x32x16_bf16(al, bh, acc2[s], 0, 0, 0);
      acc2[s] = __builtin_amdgcn_mfma_f32_32x32x16_bf16(ah, bl, acc2[s], 0, 0, 0);
    }
  }

  int rowb = wv * 32 + 4 * (lane >> 5);
  float rsv[16];
#pragma unroll
  for (int reg = 0; reg < 16; reg++) rsv[reg] = rsL[rowb + (reg & 3) + 8 * (reg >> 2)];
#pragma unroll
  for (int s = 0; s < 3; s++) {
    int n = s * 32 + ncol;
    float bn = bL[n];
#pragma unroll
    for (int reg = 0; reg < 16; reg++) {
      int r = m0 + rowb + (reg & 3) + 8 * (reg >> 2);
      float v = rsv[reg] * (acc1[s][reg] + bn) + acc2[s][reg];
      if (relu) v = fmaxf(v, 0.f);
      unsigned short h = f2bf(v);
      Oh[(size_t)r * 96 + n] = h;
      Ol[(size_t)r * 96 + n] = f2bf(v - bf2f(h));
    }
  }
}

// ---------------- MFMA final GEMM: relu(A0@Wtop + A1@Wbot + b), transpose-store ----
// grid (196, 2): blockIdx.y picks 96-col half. Bt: [192 cols][192 k] bf16 pairs.
__global__ __launch_bounds__(256) void mfma_final_kernel(
    const unsigned short* __restrict__ A0h, const unsigned short* __restrict__ A0l,
    const unsigned short* __restrict__ A1h, const unsigned short* __restrict__ A1l,
    const unsigned short* __restrict__ Bth, const unsigned short* __restrict__ Btl,
    const float* __restrict__ bias, float* __restrict__ out) {
  __shared__ float bL[96];
  __shared__ float tt[4][32][33];
  int tid = threadIdx.x, lane = tid & 63, wv = tid >> 6;
  int m0 = blockIdx.x * 128;
  int n0 = blockIdx.y * 96;
  if (tid < 96) bL[tid] = bias[n0 + tid];
  __syncthreads();

  int koff = (lane >> 5) * 8;
  int arow = m0 + wv * 32 + (lane & 31);
  const unsigned short* a0h = A0h + (size_t)arow * 96 + koff;
  const unsigned short* a0l = A0l + (size_t)arow * 96 + koff;
  const unsigned short* a1h = A1h + (size_t)arow * 96 + koff;
  const unsigned short* a1l = A1l + (size_t)arow * 96 + koff;
  int ncol = lane & 31;

  f32x16 acc[3];
#pragma unroll
  for (int s = 0; s < 3; s++)
    acc[s] = (f32x16){0.f, 0.f, 0.f, 0.f, 0.f, 0.f, 0.f, 0.f,
                      0.f, 0.f, 0.f, 0.f, 0.f, 0.f, 0.f, 0.f};

#pragma unroll
  for (int c = 0; c < 12; c++) {
    s16x8 ah, al;
    if (c < 6) {
      ah = *(const s16x8*)(a0h + c * 16);
      al = *(const s16x8*)(a0l + c * 16);
    } else {
      ah = *(const s16x8*)(a1h + (c - 6) * 16);
      al = *(const s16x8*)(a1l + (c - 6) * 16);
    }
#pragma unroll
    for (int s = 0; s < 3; s++) {
      size_t bo = (size_t)(n0 + s * 32 + ncol) * 192 + c * 16 + koff;
      s16x8 bh = *(const s16x8*)(Bth + bo);
      s16x8 bl = *(const s16x8*)(Btl + bo);
      acc[s] = __builtin_amdgcn_mfma_f32_32x32x16_bf16(ah, bh, acc[s], 0, 0, 0);
      acc[s] = __builtin_amdgcn_mfma_f32_32x32x16_bf16(al, bh, acc[s], 0, 0, 0);
      acc[s] = __builtin_amdgcn_mfma_f32_32x32x16_bf16(ah, bl, acc[s], 0, 0, 0);
    }
  }

  // epilogue: per strip, wave-local transpose then coalesced column store
  int rowb = wv * 32 + 4 * (lane >> 5);
  int gnode0 = m0 + wv * 32;
  int gbase = gnode0 + ncol;            // node for readback lanes (ncol = r_local)
  int bb = gbase / NPB, nidx = gbase % NPB;  // 32-aligned: uniform per half... per lane
#pragma unroll
  for (int s = 0; s < 3; s++) {
    int n = s * 32 + ncol;
#pragma unroll
    for (int reg = 0; reg < 16; reg++) {
      int rl = rowb - wv * 32 + (reg & 3) + 8 * (reg >> 2);
      float v = acc[s][reg] + bL[n];
      v = fmaxf(v, 0.f);
      tt[wv][ncol][rl] = v;   // tt[n_local][r_local]
    }
    __builtin_amdgcn_s_waitcnt(0);  // lgkmcnt(0): wave-local LDS write->read
#pragma unroll
    for (int i = 0; i < 16; i++) {
      int nl = 2 * i + (lane >> 5);
      float v = tt[wv][nl][ncol];
      int ng = n0 + s * 32 + nl;
      out[(size_t)bb * COUT * NPB + (size_t)ng * NPB + nidx] = v;
    }
  }
}

// ---------------- generic fp32 GEMM (kept for h64 head only) ----------------
__global__ __launch_bounds__(256) void gemm_kernel(
    const float* __restrict__ A0, int Ktot, const float* __restrict__ B, int ldb,
    const float* __restrict__ bias, float* __restrict__ Cc, int N, int relu) {
  __shared__ float As[16][68];
  __shared__ float Bs[16][68];
  int tid = threadIdx.x;
  int tx = tid & 15, ty = tid >> 4;
  int row0 = blockIdx.x * 64, col0 = blockIdx.y * 64;
  float acc[4][4] = {};
  int ai = tid >> 2;
  int ak = (tid & 3) * 4;
  int bk = tid >> 4;
  int bj = (tid & 15) * 4;

  for (int k0 = 0; k0 < Ktot; k0 += 16) {
    {
      int r = row0 + ai;
      float4 v = *(const float4*)(A0 + (size_t)r * Ktot + k0 + ak);
      As[ak + 0][ai] = v.x;
      As[ak + 1][ai] = v.y;
      As[ak + 2][ai] = v.z;
      As[ak + 3][ai] = v.w;
    }
    {
      int kg = k0 + bk;
      int j = col0 + bj;
      float4 v = make_float4(0.f, 0.f, 0.f, 0.f);
      if (j < N) v = *(const float4*)(B + (size_t)kg * ldb + j);
      *(float4*)&Bs[bk][bj] = v;
    }
    __syncthreads();
#pragma unroll
    for (int kk = 0; kk < 16; kk++) {
      float4 av = *(const float4*)&As[kk][ty * 4];
      float4 bv = *(const float4*)&Bs[kk][tx * 4];
      acc[0][0] += av.x * bv.x; acc[0][1] += av.x * bv.y; acc[0][2] += av.x * bv.z; acc[0][3] += av.x * bv.w;
      acc[1][0] += av.y * bv.x; acc[1][1] += av.y * bv.y; acc[1][2] += av.y * bv.z; acc[1][3] += av.y * bv.w;
      acc[2][0] += av.z * bv.x; acc[2][1] += av.z * bv.y; acc[2][2] += av.z * bv.z; acc[2][3] += av.z * bv.w;
      acc[3][0] += av.w * bv.x; acc[3][1] += av.w * bv.y; acc[3][2] += av.w * bv.z; acc[3][3] += av.w * bv.w;
    }
    __syncthreads();
  }
#pragma unroll
  for (int ii = 0; ii < 4; ii++) {
    int r = row0 + ty * 4 + ii;
#pragma unroll
    for (int jj = 0; jj < 4; jj++) {
      int j = col0 + tx * 4 + jj;
      if (j >= N) continue;
      float v = acc[ii][jj] + bias[j];
      if (relu) v = fmaxf(v, 0.f);
      Cc[(size_t)r * N + j] = v;
    }
  }
}

extern "C" void kernel_launch(void* const* d_in, const int* in_sizes, int n_in,
                              void* d_out, int out_size, void* d_ws, size_t ws_size,
                              hipStream_t stream) {
  const float* x      = (const float*)d_in[0];
  const float* kmap_w = (const float*)d_in[1];
  const float* kmap_b = (const float*)d_in[2];
  const float* kfc_w  = (const float*)d_in[3];
  const float* kfc_b  = (const float*)d_in[4];
  const float* kmu_w  = (const float*)d_in[5];
  const float* kmu_b  = (const float*)d_in[6];
  const float* kdec_w = (const float*)d_in[7];
  const float* kdec_b = (const float*)d_in[8];
  const float* ec1_w  = (const float*)d_in[9];
  const float* ec1_b  = (const float*)d_in[10];
  const float* ec2_w  = (const float*)d_in[11];
  const float* ec2_b  = (const float*)d_in[12];
  const float* fc_w   = (const float*)d_in[13];
  const float* fc_b   = (const float*)d_in[14];
  const float* io_w   = (const float*)d_in[15];
  const float* io_b   = (const float*)d_in[16];
  const float* up_w   = (const float*)d_in[17];
  const float* up_b   = (const float*)d_in[18];

  // ---- workspace layout (~49.8 MB, liveness-aliased) ----
  char* ws = (char*)d_ws;
  size_t off = 0;
  auto alloc = [&](size_t bytes) -> void* {
    void* p = ws + off;
    off += (bytes + 255) & ~(size_t)255;
    return p;
  };
  const size_t HBF = (size_t)NODES * C * 2;  // 4,816,896 B (256-aligned)
  float* xf   = (float*)alloc((size_t)NODES * C * 4);
  float* sqb  = (float*)alloc((size_t)NODES * 4);
  float* rs   = (float*)alloc((size_t)NODES * 4);
  int*   kint = (int*)alloc((size_t)NODES * 4);
  int*   nn   = (int*)alloc((size_t)NODES * KNN * 4);
  unsigned short* xh = (unsigned short*)alloc(HBF);   // live to the end
  unsigned short* xl = (unsigned short*)alloc(HBF);
  unsigned short* Sh = (unsigned short*)alloc(HBF);   // gather outputs
  unsigned short* Sl = (unsigned short*)alloc(HBF);
  char* region = (char*)alloc((size_t)NODES * COUT * 4);  // 19.27 MB
  // region timeline: h64buf(6.4M) -> pk_i(4.8M) -> h1 pair [0..9.6M) -> h2 pair [9.6..19.3M)
  float* h64buf = (float*)region;
  int*   pk_i   = (int*)region;
  unsigned short* h1h = (unsigned short*)region;
  unsigned short* h1l = (unsigned short*)(region + HBF);
  unsigned short* h2h = (unsigned short*)(region + 2 * HBF);
  unsigned short* h2l = (unsigned short*)(region + 3 * HBF);
  // fold weights
  float* WkP = (float*)alloc(96 * 64 * 4);
  float* bkP = (float*)alloc(64 * 4);
  float* WdP = (float*)alloc(64 * 9 * 4);
  float* bdP = (float*)alloc(16 * 4);
  float* WPf = (float*)alloc(192 * 192 * 4);
  float* bPf = (float*)alloc(192 * 4);
  unsigned short* B1h = (unsigned short*)alloc(96 * 192 * 2);
  unsigned short* B1l = (unsigned short*)alloc(96 * 192 * 2);
  unsigned short* B2h = (unsigned short*)alloc(96 * 192 * 2);
  unsigned short* B2l = (unsigned short*)alloc(96 * 192 * 2);
  unsigned short* BFh = (unsigned short*)alloc(192 * 192 * 2);
  unsigned short* BFl = (unsigned short*)alloc(192 * 192 * 2);

  transpose_kernel<<<dim3(98, 3, 8), dim3(32, 8), 0, stream>>>(x, xf);
  sqsplit_kernel<<<98, 256, 0, stream>>>(xf, sqb, xh, xl);

  // ---- VAE folds + h64 GEMM + argmax -> kint, rs ----
  foldmm_kernel<<<dim3(96, 1), 256, 0, stream>>>(kmap_w, kfc_w, nullptr, WkP, 500, 64);
  foldmm_kernel<<<dim3(1, 1), 256, 0, stream>>>(kmap_b, kfc_w, kfc_b, bkP, 500, 64);
  foldmm_kernel<<<dim3(64, 1), 256, 0, stream>>>(kmu_w, kdec_w, nullptr, WdP, 32, 9);
  foldmm_kernel<<<dim3(1, 1), 256, 0, stream>>>(kmu_b, kdec_w, kdec_b, bdP, 32, 9);
  gemm_kernel<<<dim3(392, 1), 256, 0, stream>>>(xf, 96, WkP, 64, bkP, h64buf, 64, 1);
  argmax9_kernel<<<98, 256, 0, stream>>>(h64buf, WdP, bdP, kint, rs);

  // ---- kNN filter + exact rescore ----
  knn_mfma_kernel<<<dim3(49, 8, MSPLIT), 256, 0, stream>>>(xh, xl, sqb, pk_i);
  rescore_kernel<<<6272, 256, 0, stream>>>(xf, sqb, pk_i, nn);

  // ---- weight folds for MFMA GEMMs ----
  fold_ec_bt<<<72, 256, 0, stream>>>(ec1_w, B1h, B1l);
  fold_ec_bt<<<72, 256, 0, stream>>>(ec2_w, B2h, B2l);
  foldmm_kernel<<<dim3(96, 3), 256, 0, stream>>>(io_w, up_w, nullptr, WPf, 192, 192);
  foldmm_kernel<<<dim3(96, 3), 256, 0, stream>>>(fc_w, up_w + 192 * 192, nullptr,
                                                 WPf + 96 * 192, 192, 192);
  finalbias_kernel<<<1, 192, 0, stream>>>(io_b, fc_b, up_w, up_b, bPf);
  fold_f_bt<<<144, 256, 0, stream>>>(WPf, BFh, BFl);

  // ---- EdgeConv layer 1 (relu) ----
  gather_f32_kernel<<<2352, 256, 0, stream>>>(xf, nn, kint, Sh, Sl);
  mfma_ec_kernel<<<196, 256, 0, stream>>>(xh, xl, Sh, Sl, B1h, B1l, rs, ec1_b, 1,
                                          h1h, h1l);
  // ---- EdgeConv layer 2 (no relu) ----
  gather_bf_kernel<<<2352, 256, 0, stream>>>(h1h, h1l, nn, kint, Sh, Sl);
  mfma_ec_kernel<<<196, 256, 0, stream>>>(h1h, h1l, Sh, Sl, B2h, B2l, rs, ec2_b, 0,
                                          h2h, h2l);
  // ---- final folded GEMM + transpose-store ----
  mfma_final_kernel<<<dim3(196, 2), 256, 0, stream>>>(xh, xl, h2h, h2l, BFh, BFl,
                                                      bPf, (float*)d_out);
}

// Round 13
// 544.174 us; speedup vs baseline: 1.5205x; 1.1129x over previous
//
#include <hip/hip_runtime.h>

#define NODES 25088
#define NB 8
#define NPB 3136   // nodes per batch (56*56)
#define C 96
#define KNN 9
#define COUT 192
#define MSPLIT 4   // m-range quarters for knn filter
#define T12 12     // filter depth per quarter
#define NCAND (MSPLIT * T12)  // 48 rescore candidates per query

typedef float f32x4 __attribute__((ext_vector_type(4)));
typedef float f32x16 __attribute__((ext_vector_type(16)));
typedef short s16x8 __attribute__((ext_vector_type(8)));

__device__ __forceinline__ unsigned short f2bf(float x) {
  unsigned u = __float_as_uint(x);
  return (unsigned short)((u + 0x7fffu + ((u >> 16) & 1u)) >> 16);
}
__device__ __forceinline__ float bf2f(unsigned short h) {
  return __uint_as_float(((unsigned)h) << 16);
}

// ---------------- transpose x [B,C,N] -> xf [B*N, C] ----------------
__global__ void transpose_kernel(const float* __restrict__ x, float* __restrict__ xf) {
  __shared__ float t[32][33];
  int b = blockIdx.z, ct = blockIdx.y, nt = blockIdx.x;
  int tx = threadIdx.x, ty = threadIdx.y;
  int n0 = nt * 32, c0 = ct * 32;
  const float* xb = x + (size_t)b * C * NPB;
#pragma unroll
  for (int i = 0; i < 4; i++) {
    int c = c0 + ty + i * 8;
    t[ty + i * 8][tx] = xb[(size_t)c * NPB + n0 + tx];
  }
  __syncthreads();
  float* xfb = xf + (size_t)b * NPB * C;
#pragma unroll
  for (int i = 0; i < 4; i++) {
    int n = n0 + ty + i * 8;
    xfb[(size_t)n * C + c0 + tx] = t[tx][ty + i * 8];
  }
}

// ---------------- fused per-node sq-norm + bf16 hi/lo split ----------------
__global__ void sqsplit_kernel(const float* __restrict__ xf, float* __restrict__ sq,
                               unsigned short* __restrict__ xh,
                               unsigned short* __restrict__ xl) {
  int node = blockIdx.x * 256 + threadIdx.x;
  const float4* r = (const float4*)(xf + (size_t)node * C);
  ushort4* hp = (ushort4*)(xh + (size_t)node * C);
  ushort4* lp = (ushort4*)(xl + (size_t)node * C);
  float s = 0.f;
#pragma unroll
  for (int i = 0; i < 24; i++) {
    float4 v = r[i];
    s += v.x * v.x + v.y * v.y + v.z * v.z + v.w * v.w;
    ushort4 h, l;
    h.x = f2bf(v.x); l.x = f2bf(v.x - bf2f(h.x));
    h.y = f2bf(v.y); l.y = f2bf(v.y - bf2f(h.y));
    h.z = f2bf(v.z); l.z = f2bf(v.z - bf2f(h.z));
    h.w = f2bf(v.w); l.w = f2bf(v.w - bf2f(h.w));
    hp[i] = h;
    lp[i] = l;
  }
  sq[node] = s;
}

// ---------------- ONE fused fold launch: block-role dispatch ----------------
// [0,96)  WkP row m        [96]    bkP          [97,161) WdP row    [161] bdP
// [162,234) B1 transform   [234,306) B2         [306,594) BF top (io_w@up_top)
// [594,882) BF bot (fc_w@up_bot)                [882]   bPf
__global__ void fold_all_kernel(
    const float* __restrict__ kmap_w, const float* __restrict__ kmap_b,
    const float* __restrict__ kfc_w, const float* __restrict__ kfc_b,
    const float* __restrict__ kmu_w, const float* __restrict__ kmu_b,
    const float* __restrict__ kdec_w, const float* __restrict__ kdec_b,
    const float* __restrict__ ec1_w, const float* __restrict__ ec2_w,
    const float* __restrict__ io_w, const float* __restrict__ io_b,
    const float* __restrict__ fc_w, const float* __restrict__ fc_b,
    const float* __restrict__ up_w, const float* __restrict__ up_b,
    float* __restrict__ WkP, float* __restrict__ bkP, float* __restrict__ WdP,
    float* __restrict__ bdP, float* __restrict__ bPf,
    unsigned short* __restrict__ B1h, unsigned short* __restrict__ B1l,
    unsigned short* __restrict__ B2h, unsigned short* __restrict__ B2l,
    unsigned short* __restrict__ BFh, unsigned short* __restrict__ BFl) {
  __shared__ float sh[4][64];
  int bid = blockIdx.x, tid = threadIdx.x;
  int tx = tid & 63, ty = tid >> 6;
  if (bid < 96) {
    int m = bid;
    float acc = 0.f;
    for (int k = ty; k < 500; k += 4) acc += kmap_w[m * 500 + k] * kfc_w[k * 64 + tx];
    sh[ty][tx] = acc;
    __syncthreads();
    if (ty == 0) WkP[m * 64 + tx] = sh[0][tx] + sh[1][tx] + sh[2][tx] + sh[3][tx];
  } else if (bid == 96) {
    float acc = 0.f;
    for (int k = ty; k < 500; k += 4) acc += kmap_b[k] * kfc_w[k * 64 + tx];
    sh[ty][tx] = acc;
    __syncthreads();
    if (ty == 0) bkP[tx] = sh[0][tx] + sh[1][tx] + sh[2][tx] + sh[3][tx] + kfc_b[tx];
  } else if (bid < 161) {
    int m = bid - 97;
    float acc = 0.f;
    if (tx < 9) {
      for (int k = ty; k < 32; k += 4) acc += kmu_w[m * 32 + k] * kdec_w[k * 9 + tx];
    }
    sh[ty][tx] = acc;
    __syncthreads();
    if (ty == 0 && tx < 9) WdP[m * 9 + tx] = sh[0][tx] + sh[1][tx] + sh[2][tx] + sh[3][tx];
  } else if (bid == 161) {
    float acc = 0.f;
    if (tx < 9) {
      for (int k = ty; k < 32; k += 4) acc += kmu_b[k] * kdec_w[k * 9 + tx];
    }
    sh[ty][tx] = acc;
    __syncthreads();
    if (ty == 0 && tx < 9) bdP[tx] = sh[0][tx] + sh[1][tx] + sh[2][tx] + sh[3][tx] + kdec_b[tx];
  } else if (bid < 234) {
    int t = (bid - 162) * 256 + tid;  // 72*256 = 96*192
    int n = t / 192, k = t % 192;
    float v = ec1_w[(size_t)k * 96 + n];
    if (k < 96) v -= ec1_w[(size_t)(k + 96) * 96 + n];
    unsigned short h = f2bf(v);
    B1h[t] = h;
    B1l[t] = f2bf(v - bf2f(h));
  } else if (bid < 306) {
    int t = (bid - 234) * 256 + tid;
    int n = t / 192, k = t % 192;
    float v = ec2_w[(size_t)k * 96 + n];
    if (k < 96) v -= ec2_w[(size_t)(k + 96) * 96 + n];
    unsigned short h = f2bf(v);
    B2h[t] = h;
    B2l[t] = f2bf(v - bf2f(h));
  } else if (bid < 594) {
    int r = bid - 306;
    int m = r / 3, n = (r % 3) * 64 + tx;
    float acc = 0.f;
    for (int k = ty; k < 192; k += 4) acc += io_w[m * 192 + k] * up_w[(size_t)k * 192 + n];
    sh[ty][tx] = acc;
    __syncthreads();
    if (ty == 0) {
      float v = sh[0][tx] + sh[1][tx] + sh[2][tx] + sh[3][tx];
      unsigned short h = f2bf(v);
      BFh[(size_t)n * 192 + m] = h;
      BFl[(size_t)n * 192 + m] = f2bf(v - bf2f(h));
    }
  } else if (bid < 882) {
    int r = bid - 594;
    int m = r / 3, n = (r % 3) * 64 + tx;
    float acc = 0.f;
    for (int k = ty; k < 192; k += 4)
      acc += fc_w[m * 192 + k] * up_w[(size_t)(192 + k) * 192 + n];
    sh[ty][tx] = acc;
    __syncthreads();
    if (ty == 0) {
      float v = sh[0][tx] + sh[1][tx] + sh[2][tx] + sh[3][tx];
      unsigned short h = f2bf(v);
      BFh[(size_t)n * 192 + 96 + m] = h;
      BFl[(size_t)n * 192 + 96 + m] = f2bf(v - bf2f(h));
    }
  } else {
    if (tid < 192) {
      float acc = up_b[tid];
      for (int k = 0; k < 192; k++) {
        acc += io_b[k] * up_w[k * 192 + tid];
        acc += fc_b[k] * up_w[(192 + k) * 192 + tid];
      }
      bPf[tid] = acc;
    }
  }
}

// ---------------- logits = h64 @ WdP + bdP; kint = argmax (first max) ----------------
__global__ void argmax9_kernel(const float* __restrict__ h64, const float* __restrict__ WdP,
                               const float* __restrict__ bdP, int* __restrict__ kint,
                               float* __restrict__ rs) {
  __shared__ float wd[64 * 9];
  __shared__ float bd[9];
  int tid = threadIdx.x;
  for (int f = tid; f < 576; f += 256) wd[f] = WdP[f];
  if (tid < 9) bd[tid] = bdP[tid];
  __syncthreads();
  int node = blockIdx.x * 256 + tid;
  const float4* hp = (const float4*)(h64 + (size_t)node * 64);
  float4 h[16];
#pragma unroll
  for (int i = 0; i < 16; i++) h[i] = hp[i];
  float best = -3.4e38f;
  int bi = 0;
#pragma unroll
  for (int n = 0; n < 9; n++) {
    float acc = bd[n];
#pragma unroll
    for (int k = 0; k < 16; k++) {
      float4 hv = h[k];
      acc += hv.x * wd[(4 * k + 0) * 9 + n] + hv.y * wd[(4 * k + 1) * 9 + n] +
             hv.z * wd[(4 * k + 2) * 9 + n] + hv.w * wd[(4 * k + 3) * 9 + n];
    }
    if (acc > best) { best = acc; bi = n; }
  }
  kint[node] = bi;
  rs[node] = (float)bi;
}

// ---------------- MFMA kNN filter (R9-verified, unchanged) ----------------
__global__ __launch_bounds__(256) void knn_mfma_kernel(
    const unsigned short* __restrict__ xh, const unsigned short* __restrict__ xl,
    const float* __restrict__ sq, int* __restrict__ pk_i) {
  __shared__ unsigned short mh[64 * 104];
  __shared__ float ST[64 * 68];
  __shared__ float sqs[64];
  int tid = threadIdx.x;
  int lane = tid & 63, wv = tid >> 6;
  int b = blockIdx.y, z = blockIdx.z;
  int q0 = blockIdx.x * 64;
  int bbase = b * NPB;
  int t0 = (z * 49) / MSPLIT, t1 = ((z + 1) * 49) / MSPLIT;

  int koff = (lane >> 5) * 8;
  int rowA = bbase + q0 + (wv >> 1) * 32 + (lane & 31);
  s16x8 ah[6], al[6];
  {
    const unsigned short* ph = xh + (size_t)rowA * 96 + koff;
    const unsigned short* pl = xl + (size_t)rowA * 96 + koff;
#pragma unroll
    for (int kc = 0; kc < 6; kc++) {
      ah[kc] = *(const s16x8*)(ph + kc * 16);
      al[kc] = *(const s16x8*)(pl + kc * 16);
    }
  }
  float sqr = sq[bbase + q0 + lane];

  float fd[T12];
#pragma unroll
  for (int k = 0; k < T12; k++) fd[k] = 3.4e38f;

  int srow = tid >> 2, sseg = tid & 3;

  for (int t = t0; t < t1; t++) {
    int m0 = t * 64;
    __syncthreads();
    {
      const unsigned short* gh = xh + (size_t)(bbase + m0 + srow) * 96;
#pragma unroll
      for (int i = 0; i < 3; i++) {
        int s = sseg * 3 + i;
        *(s16x8*)(mh + srow * 104 + s * 8) = *(const s16x8*)(gh + s * 8);
      }
      if (tid < 64) sqs[tid] = sq[bbase + m0 + tid];
    }
    __syncthreads();

    int mrow = (wv & 1) * 32 + (lane & 31);
    s16x8 bh[6];
#pragma unroll
    for (int kc = 0; kc < 6; kc++)
      bh[kc] = *(const s16x8*)(mh + mrow * 104 + kc * 16 + koff);

    f32x16 acc = (f32x16){0.f, 0.f, 0.f, 0.f, 0.f, 0.f, 0.f, 0.f,
                          0.f, 0.f, 0.f, 0.f, 0.f, 0.f, 0.f, 0.f};
    asm volatile(
        "s_nop 1\n\t"
        "v_mfma_f32_32x32x16_bf16 %0, %1, %13, %0\n\t"
        "v_mfma_f32_32x32x16_bf16 %0, %7, %13, %0\n\t"
        "v_mfma_f32_32x32x16_bf16 %0, %2, %14, %0\n\t"
        "v_mfma_f32_32x32x16_bf16 %0, %8, %14, %0\n\t"
        "v_mfma_f32_32x32x16_bf16 %0, %3, %15, %0\n\t"
        "v_mfma_f32_32x32x16_bf16 %0, %9, %15, %0\n\t"
        "v_mfma_f32_32x32x16_bf16 %0, %4, %16, %0\n\t"
        "v_mfma_f32_32x32x16_bf16 %0, %10, %16, %0\n\t"
        "v_mfma_f32_32x32x16_bf16 %0, %5, %17, %0\n\t"
        "v_mfma_f32_32x32x16_bf16 %0, %11, %17, %0\n\t"
        "v_mfma_f32_32x32x16_bf16 %0, %6, %18, %0\n\t"
        "v_mfma_f32_32x32x16_bf16 %0, %12, %18, %0\n\t"
        "s_nop 7\n\t"
        "s_nop 7\n\t"
        "s_nop 7"
        : "+v"(acc)
        : "v"(ah[0]), "v"(ah[1]), "v"(ah[2]), "v"(ah[3]), "v"(ah[4]), "v"(ah[5]),
          "v"(al[0]), "v"(al[1]), "v"(al[2]), "v"(al[3]), "v"(al[4]), "v"(al[5]),
          "v"(bh[0]), "v"(bh[1]), "v"(bh[2]), "v"(bh[3]), "v"(bh[4]), "v"(bh[5]));

    {
      int mcol = (wv & 1) * 32 + (lane & 31);
      int qbase = (wv >> 1) * 32 + 4 * (lane >> 5);
#pragma unroll
      for (int g = 0; g < 4; g++) {
        f32x4 v = (f32x4){acc[4 * g + 0], acc[4 * g + 1], acc[4 * g + 2], acc[4 * g + 3]};
        *(f32x4*)(ST + mcol * 68 + qbase + 8 * g) = v;
      }
    }
    __syncthreads();

    int lbase = (t - t0) * 64;
#pragma unroll
    for (int i = 0; i < 16; i++) {
      int mloc = wv * 16 + i;
      float d = fmaf(-2.f, ST[mloc * 68 + lane], sqr + sqs[mloc]);
      unsigned u = (__float_as_uint(d) & 0xFFFFFC00u) | (unsigned)(lbase + mloc);
      float key = __uint_as_float(u);
      if (key < fd[T12 - 1]) {
        float t2 = key;
#pragma unroll
        for (int k = 0; k < T12; k++) {
          float lo = fminf(fd[k], t2);
          t2 = fmaxf(fd[k], t2);
          fd[k] = lo;
        }
      }
    }
  }

  __syncthreads();
  float* cd = (float*)mh;
#pragma unroll
  for (int k = 0; k < T12; k++) cd[(wv * 64 + lane) * T12 + k] = fd[k];
  __syncthreads();
  if (wv == 0) {
    float gd[T12];
#pragma unroll
    for (int k = 0; k < T12; k++) gd[k] = 3.4e38f;
    for (int s = 0; s < 4; s++) {
#pragma unroll
      for (int k = 0; k < T12; k++) {
        float key = cd[(s * 64 + lane) * T12 + k];
        if (key < gd[T12 - 1]) {
          float t2 = key;
#pragma unroll
          for (int kk = 0; kk < T12; kk++) {
            float lo = fminf(gd[kk], t2);
            t2 = fmaxf(gd[kk], t2);
            gd[kk] = lo;
          }
        }
      }
    }
    size_t base = ((size_t)(bbase + q0 + lane) * MSPLIT + z) * T12;
#pragma unroll
    for (int k = 0; k < T12; k++) {
      int mloc = (int)(__float_as_uint(gd[k]) & 0x3FFu) + t0 * 64;
      pk_i[base + k] = bbase + mloc;
    }
  }
}

// ---------------- exact fp32 rescore (unchanged) ----------------
__global__ void rescore_kernel(const float* __restrict__ xf, const float* __restrict__ sq,
                               const int* __restrict__ pk_i, int* __restrict__ nn) {
  __shared__ float qr[4][96];
  __shared__ float sqq[4];
  __shared__ float dd[4][NCAND];
  __shared__ int jj[4][NCAND];
  int tid = threadIdx.x;
  int qloc = tid >> 6, c = tid & 63;
  int qbase = blockIdx.x * 4;
  for (int f = tid; f < 4 * 96; f += 256)
    qr[f / 96][f % 96] = xf[(size_t)(qbase + f / 96) * 96 + f % 96];
  if (tid < 4) sqq[tid] = sq[qbase + tid];
  __syncthreads();
  if (c < NCAND) {
    int q = qbase + qloc;
    int j = pk_i[(size_t)q * NCAND + c];
    const float4* qp = (const float4*)qr[qloc];
    const float4* mp = (const float4*)(xf + (size_t)j * 96);
    float d0 = 0.f, d1 = 0.f, d2 = 0.f, d3 = 0.f;
#pragma unroll
    for (int i = 0; i < 24; i++) {
      float4 qv = qp[i];
      float4 mv = mp[i];
      d0 += qv.x * mv.x;
      d1 += qv.y * mv.y;
      d2 += qv.z * mv.z;
      d3 += qv.w * mv.w;
    }
    dd[qloc][c] = (sqq[qloc] - 2.0f * ((d0 + d1) + (d2 + d3))) + sq[j];
    jj[qloc][c] = j;
  }
  __syncthreads();
  if (c == 0) {
    int q = qbase + qloc;
    float fd[KNN];
    int fi[KNN];
#pragma unroll
    for (int k = 0; k < KNN; k++) { fd[k] = 3.4e38f; fi[k] = 0x7fffffff; }
    for (int e = 0; e < NCAND; e++) {
      float d = dd[qloc][e];
      int j = jj[qloc][e];
      if (d < fd[KNN - 1] || (d == fd[KNN - 1] && j < fi[KNN - 1])) {
        fd[KNN - 1] = d;
        fi[KNN - 1] = j;
#pragma unroll
        for (int k = KNN - 1; k > 0; --k) {
          bool sw = (fd[k] < fd[k - 1]) || (fd[k] == fd[k - 1] && fi[k] < fi[k - 1]);
          if (sw) {
            float td = fd[k]; fd[k] = fd[k - 1]; fd[k - 1] = td;
            int ti = fi[k]; fi[k] = fi[k - 1]; fi[k - 1] = ti;
          }
        }
      }
    }
#pragma unroll
    for (int k = 0; k < KNN; k++) nn[(size_t)q * KNN + k] = fi[k];
  }
}

// ---------------- gather-sum (fp32 feat) -> bf16 hi/lo pair ----------------
__global__ void gather_f32_kernel(const float* __restrict__ feat, const int* __restrict__ nn,
                                  const int* __restrict__ kint,
                                  unsigned short* __restrict__ Sh,
                                  unsigned short* __restrict__ Sl) {
  int idx = blockIdx.x * 256 + threadIdx.x;
  int node = idx / 24, c4 = idx % 24;
  int kc = kint[node];
  const int* nr = nn + (size_t)node * KNN;
  float4 acc = make_float4(0.f, 0.f, 0.f, 0.f);
  for (int k = 0; k < kc; k++) {
    int j = nr[k];
    float4 v = ((const float4*)(feat + (size_t)j * C))[c4];
    acc.x += v.x; acc.y += v.y; acc.z += v.z; acc.w += v.w;
  }
  ushort4 h, l;
  h.x = f2bf(acc.x); l.x = f2bf(acc.x - bf2f(h.x));
  h.y = f2bf(acc.y); l.y = f2bf(acc.y - bf2f(h.y));
  h.z = f2bf(acc.z); l.z = f2bf(acc.z - bf2f(h.z));
  h.w = f2bf(acc.w); l.w = f2bf(acc.w - bf2f(h.w));
  ((ushort4*)(Sh + (size_t)node * C))[c4] = h;
  ((ushort4*)(Sl + (size_t)node * C))[c4] = l;
}

// ---------------- gather-sum (bf16-pair feat) -> bf16 hi/lo pair ----------------
__global__ void gather_bf_kernel(const unsigned short* __restrict__ fh,
                                 const unsigned short* __restrict__ fl,
                                 const int* __restrict__ nn, const int* __restrict__ kint,
                                 unsigned short* __restrict__ Sh,
                                 unsigned short* __restrict__ Sl) {
  int idx = blockIdx.x * 256 + threadIdx.x;
  int node = idx / 24, c4 = idx % 24;
  int kc = kint[node];
  const int* nr = nn + (size_t)node * KNN;
  float4 acc = make_float4(0.f, 0.f, 0.f, 0.f);
  for (int k = 0; k < kc; k++) {
    int j = nr[k];
    ushort4 h = ((const ushort4*)(fh + (size_t)j * C))[c4];
    ushort4 l = ((const ushort4*)(fl + (size_t)j * C))[c4];
    acc.x += bf2f(h.x) + bf2f(l.x);
    acc.y += bf2f(h.y) + bf2f(l.y);
    acc.z += bf2f(h.z) + bf2f(l.z);
    acc.w += bf2f(h.w) + bf2f(l.w);
  }
  ushort4 h, l;
  h.x = f2bf(acc.x); l.x = f2bf(acc.x - bf2f(h.x));
  h.y = f2bf(acc.y); l.y = f2bf(acc.y - bf2f(h.y));
  h.z = f2bf(acc.z); l.z = f2bf(acc.z - bf2f(h.z));
  h.w = f2bf(acc.w); l.w = f2bf(acc.w - bf2f(h.w));
  ((ushort4*)(Sh + (size_t)node * C))[c4] = h;
  ((ushort4*)(Sl + (size_t)node * C))[c4] = l;
}

// ---------------- MFMA EdgeConv GEMM: 1 wave = 32 rows x 32 cols ----------------
// out = rs .* (A0@Btop + bias) + A1@Bbot (relu opt), bf16 pair out.
// block 192 = 3 waves (one 32-col strip each); grid 784 (M-tile 32) -> 2352 waves.
__global__ __launch_bounds__(192) void mfma_ec_kernel(
    const unsigned short* __restrict__ A0h, const unsigned short* __restrict__ A0l,
    const unsigned short* __restrict__ A1h, const unsigned short* __restrict__ A1l,
    const unsigned short* __restrict__ Bth, const unsigned short* __restrict__ Btl,
    const float* __restrict__ rs, const float* __restrict__ bias, int relu,
    unsigned short* __restrict__ Oh, unsigned short* __restrict__ Ol) {
  __shared__ float rsL[32];
  __shared__ float bL[96];
  int tid = threadIdx.x, lane = tid & 63, wv = tid >> 6;
  int m0 = blockIdx.x * 32;
  if (tid < 32) rsL[tid] = rs[m0 + tid];
  if (tid < 96) bL[tid] = bias[tid];
  __syncthreads();

  int koff = (lane >> 5) * 8;
  int arow = m0 + (lane & 31);
  const unsigned short* a0h = A0h + (size_t)arow * 96 + koff;
  const unsigned short* a0l = A0l + (size_t)arow * 96 + koff;
  const unsigned short* a1h = A1h + (size_t)arow * 96 + koff;
  const unsigned short* a1l = A1l + (size_t)arow * 96 + koff;
  int n = wv * 32 + (lane & 31);

  f32x16 acc1 = (f32x16){0.f, 0.f, 0.f, 0.f, 0.f, 0.f, 0.f, 0.f,
                         0.f, 0.f, 0.f, 0.f, 0.f, 0.f, 0.f, 0.f};
  f32x16 acc2 = acc1;

#pragma unroll
  for (int c = 0; c < 6; c++) {
    s16x8 ah = *(const s16x8*)(a0h + c * 16);
    s16x8 al = *(const s16x8*)(a0l + c * 16);
    size_t bo = (size_t)n * 192 + c * 16 + koff;
    s16x8 bh = *(const s16x8*)(Bth + bo);
    s16x8 bl = *(const s16x8*)(Btl + bo);
    acc1 = __builtin_amdgcn_mfma_f32_32x32x16_bf16(ah, bh, acc1, 0, 0, 0);
    acc1 = __builtin_amdgcn_mfma_f32_32x32x16_bf16(al, bh, acc1, 0, 0, 0);
    acc1 = __builtin_amdgcn_mfma_f32_32x32x16_bf16(ah, bl, acc1, 0, 0, 0);
  }
#pragma unroll
  for (int c = 6; c < 12; c++) {
    s16x8 ah = *(const s16x8*)(a1h + (c - 6) * 16);
    s16x8 al = *(const s16x8*)(a1l + (c - 6) * 16);
    size_t bo = (size_t)n * 192 + c * 16 + koff;
    s16x8 bh = *(const s16x8*)(Bth + bo);
    s16x8 bl = *(const s16x8*)(Btl + bo);
    acc2 = __builtin_amdgcn_mfma_f32_32x32x16_bf16(ah, bh, acc2, 0, 0, 0);
    acc2 = __builtin_amdgcn_mfma_f32_32x32x16_bf16(al, bh, acc2, 0, 0, 0);
    acc2 = __builtin_amdgcn_mfma_f32_32x32x16_bf16(ah, bl, acc2, 0, 0, 0);
  }

  float bn = bL[n];
#pragma unroll
  for (int reg = 0; reg < 16; reg++) {
    int rl = (reg & 3) + 8 * (reg >> 2) + 4 * (lane >> 5);
    int r = m0 + rl;
    float v = rsL[rl] * (acc1[reg] + bn) + acc2[reg];
    if (relu) v = fmaxf(v, 0.f);
    unsigned short h = f2bf(v);
    Oh[(size_t)r * 96 + n] = h;
    Ol[(size_t)r * 96 + n] = f2bf(v - bf2f(h));
  }
}

// ---------------- MFMA final GEMM + transpose-store: grid (784, 2), block 192 ----
__global__ __launch_bounds__(192) void mfma_final_kernel(
    const unsigned short* __restrict__ A0h, const unsigned short* __restrict__ A0l,
    const unsigned short* __restrict__ A1h, const unsigned short* __restrict__ A1l,
    const unsigned short* __restrict__ Bth, const unsigned short* __restrict__ Btl,
    const float* __restrict__ bias, float* __restrict__ out) {
  __shared__ float bL[96];
  __shared__ float tt[3][32][33];
  int tid = threadIdx.x, lane = tid & 63, wv = tid >> 6;
  int m0 = blockIdx.x * 32;
  int n0 = blockIdx.y * 96;
  if (tid < 96) bL[tid] = bias[n0 + tid];
  __syncthreads();

  int koff = (lane >> 5) * 8;
  int arow = m0 + (lane & 31);
  const unsigned short* a0h = A0h + (size_t)arow * 96 + koff;
  const unsigned short* a0l = A0l + (size_t)arow * 96 + koff;
  const unsigned short* a1h = A1h + (size_t)arow * 96 + koff;
  const unsigned short* a1l = A1l + (size_t)arow * 96 + koff;
  int nloc = lane & 31;
  int n = n0 + wv * 32 + nloc;

  f32x16 acc = (f32x16){0.f, 0.f, 0.f, 0.f, 0.f, 0.f, 0.f, 0.f,
                        0.f, 0.f, 0.f, 0.f, 0.f, 0.f, 0.f, 0.f};
#pragma unroll
  for (int c = 0; c < 12; c++) {
    s16x8 ah, al;
    if (c < 6) {
      ah = *(const s16x8*)(a0h + c * 16);
      al = *(const s16x8*)(a0l + c * 16);
    } else {
      ah = *(const s16x8*)(a1h + (c - 6) * 16);
      al = *(const s16x8*)(a1l + (c - 6) * 16);
    }
    size_t bo = (size_t)n * 192 + c * 16 + koff;
    s16x8 bh = *(const s16x8*)(Bth + bo);
    s16x8 bl = *(const s16x8*)(Btl + bo);
    acc = __builtin_amdgcn_mfma_f32_32x32x16_bf16(ah, bh, acc, 0, 0, 0);
    acc = __builtin_amdgcn_mfma_f32_32x32x16_bf16(al, bh, acc, 0, 0, 0);
    acc = __builtin_amdgcn_mfma_f32_32x32x16_bf16(ah, bl, acc, 0, 0, 0);
  }

  float bn = bL[wv * 32 + nloc];
#pragma unroll
  for (int reg = 0; reg < 16; reg++) {
    int rl = (reg & 3) + 8 * (reg >> 2) + 4 * (lane >> 5);
    tt[wv][nloc][rl] = fmaxf(acc[reg] + bn, 0.f);
  }
  __builtin_amdgcn_s_waitcnt(0);  // wave-local LDS write->read (R12-proven)
  int gbase = m0 + nloc;  // 32-row tile lies within one batch (3136 % 32 == 0)
  int bb = gbase / NPB, nidx = gbase % NPB;
#pragma unroll
  for (int i = 0; i < 16; i++) {
    int nl = 2 * i + (lane >> 5);
    float v = tt[wv][nl][nloc];
    int ng = n0 + wv * 32 + nl;
    out[(size_t)bb * COUT * NPB + (size_t)ng * NPB + nidx] = v;
  }
}

// ---------------- fp32 GEMM (h64 head only) ----------------
__global__ __launch_bounds__(256) void gemm_kernel(
    const float* __restrict__ A0, int Ktot, const float* __restrict__ B, int ldb,
    const float* __restrict__ bias, float* __restrict__ Cc, int N, int relu) {
  __shared__ float As[16][68];
  __shared__ float Bs[16][68];
  int tid = threadIdx.x;
  int tx = tid & 15, ty = tid >> 4;
  int row0 = blockIdx.x * 64, col0 = blockIdx.y * 64;
  float acc[4][4] = {};
  int ai = tid >> 2;
  int ak = (tid & 3) * 4;
  int bk = tid >> 4;
  int bj = (tid & 15) * 4;

  for (int k0 = 0; k0 < Ktot; k0 += 16) {
    {
      int r = row0 + ai;
      float4 v = *(const float4*)(A0 + (size_t)r * Ktot + k0 + ak);
      As[ak + 0][ai] = v.x;
      As[ak + 1][ai] = v.y;
      As[ak + 2][ai] = v.z;
      As[ak + 3][ai] = v.w;
    }
    {
      int kg = k0 + bk;
      int j = col0 + bj;
      float4 v = make_float4(0.f, 0.f, 0.f, 0.f);
      if (j < N) v = *(const float4*)(B + (size_t)kg * ldb + j);
      *(float4*)&Bs[bk][bj] = v;
    }
    __syncthreads();
#pragma unroll
    for (int kk = 0; kk < 16; kk++) {
      float4 av = *(const float4*)&As[kk][ty * 4];
      float4 bv = *(const float4*)&Bs[kk][tx * 4];
      acc[0][0] += av.x * bv.x; acc[0][1] += av.x * bv.y; acc[0][2] += av.x * bv.z; acc[0][3] += av.x * bv.w;
      acc[1][0] += av.y * bv.x; acc[1][1] += av.y * bv.y; acc[1][2] += av.y * bv.z; acc[1][3] += av.y * bv.w;
      acc[2][0] += av.z * bv.x; acc[2][1] += av.z * bv.y; acc[2][2] += av.z * bv.z; acc[2][3] += av.z * bv.w;
      acc[3][0] += av.w * bv.x; acc[3][1] += av.w * bv.y; acc[3][2] += av.w * bv.z; acc[3][3] += av.w * bv.w;
    }
    __syncthreads();
  }
#pragma unroll
  for (int ii = 0; ii < 4; ii++) {
    int r = row0 + ty * 4 + ii;
#pragma unroll
    for (int jj = 0; jj < 4; jj++) {
      int j = col0 + tx * 4 + jj;
      if (j >= N) continue;
      float v = acc[ii][jj] + bias[j];
      if (relu) v = fmaxf(v, 0.f);
      Cc[(size_t)r * N + j] = v;
    }
  }
}

extern "C" void kernel_launch(void* const* d_in, const int* in_sizes, int n_in,
                              void* d_out, int out_size, void* d_ws, size_t ws_size,
                              hipStream_t stream) {
  const float* x      = (const float*)d_in[0];
  const float* kmap_w = (const float*)d_in[1];
  const float* kmap_b = (const float*)d_in[2];
  const float* kfc_w  = (const float*)d_in[3];
  const float* kfc_b  = (const float*)d_in[4];
  const float* kmu_w  = (const float*)d_in[5];
  const float* kmu_b  = (const float*)d_in[6];
  const float* kdec_w = (const float*)d_in[7];
  const float* kdec_b = (const float*)d_in[8];
  const float* ec1_w  = (const float*)d_in[9];
  const float* ec1_b  = (const float*)d_in[10];
  const float* ec2_w  = (const float*)d_in[11];
  const float* ec2_b  = (const float*)d_in[12];
  const float* fc_w   = (const float*)d_in[13];
  const float* fc_b   = (const float*)d_in[14];
  const float* io_w   = (const float*)d_in[15];
  const float* io_b   = (const float*)d_in[16];
  const float* up_w   = (const float*)d_in[17];
  const float* up_b   = (const float*)d_in[18];

  // ---- workspace layout (liveness-aliased) ----
  char* ws = (char*)d_ws;
  size_t off = 0;
  auto alloc = [&](size_t bytes) -> void* {
    void* p = ws + off;
    off += (bytes + 255) & ~(size_t)255;
    return p;
  };
  const size_t HBF = (size_t)NODES * C * 2;  // bf16 plane (256-aligned)
  float* xf   = (float*)alloc((size_t)NODES * C * 4);
  float* sqb  = (float*)alloc((size_t)NODES * 4);
  float* rs   = (float*)alloc((size_t)NODES * 4);
  int*   kint = (int*)alloc((size_t)NODES * 4);
  int*   nn   = (int*)alloc((size_t)NODES * KNN * 4);
  unsigned short* xh = (unsigned short*)alloc(HBF);
  unsigned short* xl = (unsigned short*)alloc(HBF);
  unsigned short* Sh = (unsigned short*)alloc(HBF);
  unsigned short* Sl = (unsigned short*)alloc(HBF);
  char* region = (char*)alloc((size_t)NODES * COUT * 4);
  // region timeline: h64buf(6.4M) -> pk_i(4.8M) -> h1 pair -> h2 pair (serial)
  float* h64buf = (float*)region;
  int*   pk_i   = (int*)region;
  unsigned short* h1h = (unsigned short*)region;
  unsigned short* h1l = (unsigned short*)(region + HBF);
  unsigned short* h2h = (unsigned short*)(region + 2 * HBF);
  unsigned short* h2l = (unsigned short*)(region + 3 * HBF);
  float* WkP = (float*)alloc(96 * 64 * 4);
  float* bkP = (float*)alloc(64 * 4);
  float* WdP = (float*)alloc(64 * 9 * 4);
  float* bdP = (float*)alloc(16 * 4);
  float* bPf = (float*)alloc(192 * 4);
  unsigned short* B1h = (unsigned short*)alloc(96 * 192 * 2);
  unsigned short* B1l = (unsigned short*)alloc(96 * 192 * 2);
  unsigned short* B2h = (unsigned short*)alloc(96 * 192 * 2);
  unsigned short* B2l = (unsigned short*)alloc(96 * 192 * 2);
  unsigned short* BFh = (unsigned short*)alloc(192 * 192 * 2);
  unsigned short* BFl = (unsigned short*)alloc(192 * 192 * 2);

  transpose_kernel<<<dim3(98, 3, 8), dim3(32, 8), 0, stream>>>(x, xf);
  sqsplit_kernel<<<98, 256, 0, stream>>>(xf, sqb, xh, xl);

  // ---- one fused fold launch (replaces 10 kernels) ----
  fold_all_kernel<<<883, 256, 0, stream>>>(
      kmap_w, kmap_b, kfc_w, kfc_b, kmu_w, kmu_b, kdec_w, kdec_b, ec1_w, ec2_w,
      io_w, io_b, fc_w, fc_b, up_w, up_b,
      WkP, bkP, WdP, bdP, bPf, B1h, B1l, B2h, B2l, BFh, BFl);

  // ---- VAE head: h64 GEMM + argmax -> kint, rs ----
  gemm_kernel<<<dim3(392, 1), 256, 0, stream>>>(xf, 96, WkP, 64, bkP, h64buf, 64, 1);
  argmax9_kernel<<<98, 256, 0, stream>>>(h64buf, WdP, bdP, kint, rs);

  // ---- kNN filter + exact rescore ----
  knn_mfma_kernel<<<dim3(49, 8, MSPLIT), 256, 0, stream>>>(xh, xl, sqb, pk_i);
  rescore_kernel<<<6272, 256, 0, stream>>>(xf, sqb, pk_i, nn);

  // ---- EdgeConv layer 1 (relu) ----
  gather_f32_kernel<<<2352, 256, 0, stream>>>(xf, nn, kint, Sh, Sl);
  mfma_ec_kernel<<<784, 192, 0, stream>>>(xh, xl, Sh, Sl, B1h, B1l, rs, ec1_b, 1,
                                          h1h, h1l);
  // ---- EdgeConv layer 2 (no relu) ----
  gather_bf_kernel<<<2352, 256, 0, stream>>>(h1h, h1l, nn, kint, Sh, Sl);
  mfma_ec_kernel<<<784, 192, 0, stream>>>(h1h, h1l, Sh, Sl, B2h, B2l, rs, ec2_b, 0,
                                          h2h, h2l);
  // ---- final folded GEMM + transpose-store ----
  mfma_final_kernel<<<dim3(784, 2), 192, 0, stream>>>(xh, xl, h2h, h2l, BFh, BFl,
                                                      bPf, (float*)d_out);
}

// Round 14
// 534.868 us; speedup vs baseline: 1.5469x; 1.0174x over previous
//
#include <hip/hip_runtime.h>

#define NODES 25088
#define NB 8
#define NPB 3136   // nodes per batch (56*56)
#define C 96
#define KNN 9
#define COUT 192
#define MSPLIT 4   // m-range quarters for knn filter
#define T12 12     // filter depth per quarter
#define NCAND (MSPLIT * T12)  // 48 rescore candidates per query

typedef float f32x4 __attribute__((ext_vector_type(4)));
typedef float f32x16 __attribute__((ext_vector_type(16)));
typedef short s16x8 __attribute__((ext_vector_type(8)));

__device__ __forceinline__ unsigned short f2bf(float x) {
  unsigned u = __float_as_uint(x);
  return (unsigned short)((u + 0x7fffu + ((u >> 16) & 1u)) >> 16);
}
__device__ __forceinline__ float bf2f(unsigned short h) {
  return __uint_as_float(((unsigned)h) << 16);
}

// ---------------- transpose x [B,C,N] -> xf [B*N, C] ----------------
__global__ void transpose_kernel(const float* __restrict__ x, float* __restrict__ xf) {
  __shared__ float t[32][33];
  int b = blockIdx.z, ct = blockIdx.y, nt = blockIdx.x;
  int tx = threadIdx.x, ty = threadIdx.y;
  int n0 = nt * 32, c0 = ct * 32;
  const float* xb = x + (size_t)b * C * NPB;
#pragma unroll
  for (int i = 0; i < 4; i++) {
    int c = c0 + ty + i * 8;
    t[ty + i * 8][tx] = xb[(size_t)c * NPB + n0 + tx];
  }
  __syncthreads();
  float* xfb = xf + (size_t)b * NPB * C;
#pragma unroll
  for (int i = 0; i < 4; i++) {
    int n = n0 + ty + i * 8;
    xfb[(size_t)n * C + c0 + tx] = t[tx][ty + i * 8];
  }
}

// ---------------- fused per-node sq-norm + bf16 hi/lo split ----------------
__global__ void sqsplit_kernel(const float* __restrict__ xf, float* __restrict__ sq,
                               unsigned short* __restrict__ xh,
                               unsigned short* __restrict__ xl) {
  int node = blockIdx.x * 256 + threadIdx.x;
  const float4* r = (const float4*)(xf + (size_t)node * C);
  ushort4* hp = (ushort4*)(xh + (size_t)node * C);
  ushort4* lp = (ushort4*)(xl + (size_t)node * C);
  float s = 0.f;
#pragma unroll
  for (int i = 0; i < 24; i++) {
    float4 v = r[i];
    s += v.x * v.x + v.y * v.y + v.z * v.z + v.w * v.w;
    ushort4 h, l;
    h.x = f2bf(v.x); l.x = f2bf(v.x - bf2f(h.x));
    h.y = f2bf(v.y); l.y = f2bf(v.y - bf2f(h.y));
    h.z = f2bf(v.z); l.z = f2bf(v.z - bf2f(h.z));
    h.w = f2bf(v.w); l.w = f2bf(v.w - bf2f(h.w));
    hp[i] = h;
    lp[i] = l;
  }
  sq[node] = s;
}

// ---------------- ONE fused fold launch: block-role dispatch ----------------
__global__ void fold_all_kernel(
    const float* __restrict__ kmap_w, const float* __restrict__ kmap_b,
    const float* __restrict__ kfc_w, const float* __restrict__ kfc_b,
    const float* __restrict__ kmu_w, const float* __restrict__ kmu_b,
    const float* __restrict__ kdec_w, const float* __restrict__ kdec_b,
    const float* __restrict__ ec1_w, const float* __restrict__ ec2_w,
    const float* __restrict__ io_w, const float* __restrict__ io_b,
    const float* __restrict__ fc_w, const float* __restrict__ fc_b,
    const float* __restrict__ up_w, const float* __restrict__ up_b,
    float* __restrict__ WkP, float* __restrict__ bkP, float* __restrict__ WdP,
    float* __restrict__ bdP, float* __restrict__ bPf,
    unsigned short* __restrict__ B1h, unsigned short* __restrict__ B1l,
    unsigned short* __restrict__ B2h, unsigned short* __restrict__ B2l,
    unsigned short* __restrict__ BFh, unsigned short* __restrict__ BFl) {
  __shared__ float sh[4][64];
  int bid = blockIdx.x, tid = threadIdx.x;
  int tx = tid & 63, ty = tid >> 6;
  if (bid < 96) {
    int m = bid;
    float acc = 0.f;
    for (int k = ty; k < 500; k += 4) acc += kmap_w[m * 500 + k] * kfc_w[k * 64 + tx];
    sh[ty][tx] = acc;
    __syncthreads();
    if (ty == 0) WkP[m * 64 + tx] = sh[0][tx] + sh[1][tx] + sh[2][tx] + sh[3][tx];
  } else if (bid == 96) {
    float acc = 0.f;
    for (int k = ty; k < 500; k += 4) acc += kmap_b[k] * kfc_w[k * 64 + tx];
    sh[ty][tx] = acc;
    __syncthreads();
    if (ty == 0) bkP[tx] = sh[0][tx] + sh[1][tx] + sh[2][tx] + sh[3][tx] + kfc_b[tx];
  } else if (bid < 161) {
    int m = bid - 97;
    float acc = 0.f;
    if (tx < 9) {
      for (int k = ty; k < 32; k += 4) acc += kmu_w[m * 32 + k] * kdec_w[k * 9 + tx];
    }
    sh[ty][tx] = acc;
    __syncthreads();
    if (ty == 0 && tx < 9) WdP[m * 9 + tx] = sh[0][tx] + sh[1][tx] + sh[2][tx] + sh[3][tx];
  } else if (bid == 161) {
    float acc = 0.f;
    if (tx < 9) {
      for (int k = ty; k < 32; k += 4) acc += kmu_b[k] * kdec_w[k * 9 + tx];
    }
    sh[ty][tx] = acc;
    __syncthreads();
    if (ty == 0 && tx < 9) bdP[tx] = sh[0][tx] + sh[1][tx] + sh[2][tx] + sh[3][tx] + kdec_b[tx];
  } else if (bid < 234) {
    int t = (bid - 162) * 256 + tid;  // 72*256 = 96*192
    int n = t / 192, k = t % 192;
    float v = ec1_w[(size_t)k * 96 + n];
    if (k < 96) v -= ec1_w[(size_t)(k + 96) * 96 + n];
    unsigned short h = f2bf(v);
    B1h[t] = h;
    B1l[t] = f2bf(v - bf2f(h));
  } else if (bid < 306) {
    int t = (bid - 234) * 256 + tid;
    int n = t / 192, k = t % 192;
    float v = ec2_w[(size_t)k * 96 + n];
    if (k < 96) v -= ec2_w[(size_t)(k + 96) * 96 + n];
    unsigned short h = f2bf(v);
    B2h[t] = h;
    B2l[t] = f2bf(v - bf2f(h));
  } else if (bid < 594) {
    int r = bid - 306;
    int m = r / 3, n = (r % 3) * 64 + tx;
    float acc = 0.f;
    for (int k = ty; k < 192; k += 4) acc += io_w[m * 192 + k] * up_w[(size_t)k * 192 + n];
    sh[ty][tx] = acc;
    __syncthreads();
    if (ty == 0) {
      float v = sh[0][tx] + sh[1][tx] + sh[2][tx] + sh[3][tx];
      unsigned short h = f2bf(v);
      BFh[(size_t)n * 192 + m] = h;
      BFl[(size_t)n * 192 + m] = f2bf(v - bf2f(h));
    }
  } else if (bid < 882) {
    int r = bid - 594;
    int m = r / 3, n = (r % 3) * 64 + tx;
    float acc = 0.f;
    for (int k = ty; k < 192; k += 4)
      acc += fc_w[m * 192 + k] * up_w[(size_t)(192 + k) * 192 + n];
    sh[ty][tx] = acc;
    __syncthreads();
    if (ty == 0) {
      float v = sh[0][tx] + sh[1][tx] + sh[2][tx] + sh[3][tx];
      unsigned short h = f2bf(v);
      BFh[(size_t)n * 192 + 96 + m] = h;
      BFl[(size_t)n * 192 + 96 + m] = f2bf(v - bf2f(h));
    }
  } else {
    if (tid < 192) {
      float acc = up_b[tid];
      for (int k = 0; k < 192; k++) {
        acc += io_b[k] * up_w[k * 192 + tid];
        acc += fc_b[k] * up_w[(192 + k) * 192 + tid];
      }
      bPf[tid] = acc;
    }
  }
}

// ---------------- logits = h64 @ WdP + bdP; kint = argmax (first max) ----------------
__global__ void argmax9_kernel(const float* __restrict__ h64, const float* __restrict__ WdP,
                               const float* __restrict__ bdP, int* __restrict__ kint,
                               float* __restrict__ rs) {
  __shared__ float wd[64 * 9];
  __shared__ float bd[9];
  int tid = threadIdx.x;
  for (int f = tid; f < 576; f += 256) wd[f] = WdP[f];
  if (tid < 9) bd[tid] = bdP[tid];
  __syncthreads();
  int node = blockIdx.x * 256 + tid;
  const float4* hp = (const float4*)(h64 + (size_t)node * 64);
  float4 h[16];
#pragma unroll
  for (int i = 0; i < 16; i++) h[i] = hp[i];
  float best = -3.4e38f;
  int bi = 0;
#pragma unroll
  for (int n = 0; n < 9; n++) {
    float acc = bd[n];
#pragma unroll
    for (int k = 0; k < 16; k++) {
      float4 hv = h[k];
      acc += hv.x * wd[(4 * k + 0) * 9 + n] + hv.y * wd[(4 * k + 1) * 9 + n] +
             hv.z * wd[(4 * k + 2) * 9 + n] + hv.w * wd[(4 * k + 3) * 9 + n];
    }
    if (acc > best) { best = acc; bi = n; }
  }
  kint[node] = bi;
  rs[node] = (float)bi;
}

// ---------------- MFMA kNN filter v2: S' = M @ Q^T (operand swap) ----------------
// grid (49, 8, MSPLIT), block 256 (4 waves: wm=wv>>1 m-quadrant, wq=wv&1 q-quadrant).
// C/D col = lane&31 = QUERY -> each lane scans its 16 m-candidates IN REGISTERS:
// no S round-trip, no strided LDS writes, 2 barriers/tile, LDS 13.6 KB.
// One-sided split: M bf16-hi x (Q hi + Q lo) -- same error model as R9 (verified).
__global__ __launch_bounds__(256) void knn_mfma_kernel(
    const unsigned short* __restrict__ xh, const unsigned short* __restrict__ xl,
    const float* __restrict__ sq, int* __restrict__ pk_i) {
  __shared__ unsigned short mh[64 * 104];  // 13312 B (bf16-hi m-tile)
  __shared__ float sqs[64];
  int tid = threadIdx.x;
  int lane = tid & 63, wv = tid >> 6;
  int wm = wv >> 1, wq = wv & 1;
  int b = blockIdx.y, z = blockIdx.z;
  int q0 = blockIdx.x * 64;
  int bbase = b * NPB;
  int t0 = (z * 49) / MSPLIT, t1 = ((z + 1) * 49) / MSPLIT;

  int koff = (lane >> 5) * 8;
  // B-fragments: this wave's 32 queries (fixed across tiles): B[k][q=lane&31]
  int qrow = bbase + q0 + wq * 32 + (lane & 31);
  s16x8 bqh[6], bql[6];
  {
    const unsigned short* ph = xh + (size_t)qrow * 96 + koff;
    const unsigned short* pl = xl + (size_t)qrow * 96 + koff;
#pragma unroll
    for (int kc = 0; kc < 6; kc++) {
      bqh[kc] = *(const s16x8*)(ph + kc * 16);
      bql[kc] = *(const s16x8*)(pl + kc * 16);
    }
  }
  float sqr = sq[qrow];  // this lane's query norm

  float fd[T12];
#pragma unroll
  for (int k = 0; k < T12; k++) fd[k] = 3.4e38f;

  int srow = tid >> 2, sseg = tid & 3;  // staging: 4 threads/row, 3 segs each

  for (int t = t0; t < t1; t++) {
    int m0 = t * 64;
    __syncthreads();
    {
      const unsigned short* gh = xh + (size_t)(bbase + m0 + srow) * 96;
#pragma unroll
      for (int i = 0; i < 3; i++) {
        int s = sseg * 3 + i;
        *(s16x8*)(mh + srow * 104 + s * 8) = *(const s16x8*)(gh + s * 8);
      }
      if (tid < 64) sqs[tid] = sq[bbase + m0 + tid];
    }
    __syncthreads();

    // A-fragments: m-rows from LDS: A[m=lane&31][k=(lane>>5)*8+j]
    int mrow = wm * 32 + (lane & 31);
    f32x16 acc = (f32x16){0.f, 0.f, 0.f, 0.f, 0.f, 0.f, 0.f, 0.f,
                          0.f, 0.f, 0.f, 0.f, 0.f, 0.f, 0.f, 0.f};
#pragma unroll
    for (int kc = 0; kc < 6; kc++) {
      s16x8 amh = *(const s16x8*)(mh + mrow * 104 + kc * 16 + koff);
      acc = __builtin_amdgcn_mfma_f32_32x32x16_bf16(amh, bqh[kc], acc, 0, 0, 0);
      acc = __builtin_amdgcn_mfma_f32_32x32x16_bf16(amh, bql[kc], acc, 0, 0, 0);
    }

    // in-register scan: lane's query is fixed; rows are this wave's m-quadrant
    int lbase = (t - t0) * 64;
#pragma unroll
    for (int reg = 0; reg < 16; reg++) {
      int mloc = wm * 32 + (reg & 3) + 8 * (reg >> 2) + 4 * (lane >> 5);
      float d = fmaf(-2.f, acc[reg], sqr + sqs[mloc]);
      unsigned u = (__float_as_uint(d) & 0xFFFFFC00u) | (unsigned)(lbase + mloc);
      float key = __uint_as_float(u);
      if (key < fd[T12 - 1]) {
        float t2 = key;
#pragma unroll
        for (int k = 0; k < T12; k++) {
          float lo = fminf(fd[k], t2);
          t2 = fmaxf(fd[k], t2);
          fd[k] = lo;
        }
      }
    }
  }

  // merge 4 partial lists per query via LDS (aliases dead mh)
  __syncthreads();
  float* cd = (float*)mh;  // 256*12 floats = 12288 B <= 13312
#pragma unroll
  for (int k = 0; k < T12; k++) cd[(wv * 64 + lane) * T12 + k] = fd[k];
  __syncthreads();
  if (wv == 0) {
    // lane = query q in [0,64): partials at waves (q>>5) and (q>>5)+2,
    // lanes (q&31) and (q&31)+32 (disjoint m coverage)
    int wva = lane >> 5, ql = lane & 31;
    int src[4] = {wva * 64 + ql, wva * 64 + ql + 32,
                  (wva + 2) * 64 + ql, (wva + 2) * 64 + ql + 32};
    float gd[T12];
#pragma unroll
    for (int k = 0; k < T12; k++) gd[k] = 3.4e38f;
#pragma unroll
    for (int s = 0; s < 4; s++) {
#pragma unroll
      for (int k = 0; k < T12; k++) {
        float key = cd[src[s] * T12 + k];
        if (key < gd[T12 - 1]) {
          float t2 = key;
#pragma unroll
          for (int kk = 0; kk < T12; kk++) {
            float lo = fminf(gd[kk], t2);
            t2 = fmaxf(gd[kk], t2);
            gd[kk] = lo;
          }
        }
      }
    }
    size_t base = ((size_t)(bbase + q0 + lane) * MSPLIT + z) * T12;
#pragma unroll
    for (int k = 0; k < T12; k++) {
      int mloc = (int)(__float_as_uint(gd[k]) & 0x3FFu) + t0 * 64;
      pk_i[base + k] = bbase + mloc;
    }
  }
}

// ---------------- exact fp32 rescore (unchanged) ----------------
__global__ void rescore_kernel(const float* __restrict__ xf, const float* __restrict__ sq,
                               const int* __restrict__ pk_i, int* __restrict__ nn) {
  __shared__ float qr[4][96];
  __shared__ float sqq[4];
  __shared__ float dd[4][NCAND];
  __shared__ int jj[4][NCAND];
  int tid = threadIdx.x;
  int qloc = tid >> 6, c = tid & 63;
  int qbase = blockIdx.x * 4;
  for (int f = tid; f < 4 * 96; f += 256)
    qr[f / 96][f % 96] = xf[(size_t)(qbase + f / 96) * 96 + f % 96];
  if (tid < 4) sqq[tid] = sq[qbase + tid];
  __syncthreads();
  if (c < NCAND) {
    int q = qbase + qloc;
    int j = pk_i[(size_t)q * NCAND + c];
    const float4* qp = (const float4*)qr[qloc];
    const float4* mp = (const float4*)(xf + (size_t)j * 96);
    float d0 = 0.f, d1 = 0.f, d2 = 0.f, d3 = 0.f;
#pragma unroll
    for (int i = 0; i < 24; i++) {
      float4 qv = qp[i];
      float4 mv = mp[i];
      d0 += qv.x * mv.x;
      d1 += qv.y * mv.y;
      d2 += qv.z * mv.z;
      d3 += qv.w * mv.w;
    }
    dd[qloc][c] = (sqq[qloc] - 2.0f * ((d0 + d1) + (d2 + d3))) + sq[j];
    jj[qloc][c] = j;
  }
  __syncthreads();
  if (c == 0) {
    int q = qbase + qloc;
    float fd[KNN];
    int fi[KNN];
#pragma unroll
    for (int k = 0; k < KNN; k++) { fd[k] = 3.4e38f; fi[k] = 0x7fffffff; }
    for (int e = 0; e < NCAND; e++) {
      float d = dd[qloc][e];
      int j = jj[qloc][e];
      if (d < fd[KNN - 1] || (d == fd[KNN - 1] && j < fi[KNN - 1])) {
        fd[KNN - 1] = d;
        fi[KNN - 1] = j;
#pragma unroll
        for (int k = KNN - 1; k > 0; --k) {
          bool sw = (fd[k] < fd[k - 1]) || (fd[k] == fd[k - 1] && fi[k] < fi[k - 1]);
          if (sw) {
            float td = fd[k]; fd[k] = fd[k - 1]; fd[k - 1] = td;
            int ti = fi[k]; fi[k] = fi[k - 1]; fi[k - 1] = ti;
          }
        }
      }
    }
#pragma unroll
    for (int k = 0; k < KNN; k++) nn[(size_t)q * KNN + k] = fi[k];
  }
}

// ---------------- gather-sum (fp32 feat) -> bf16 hi/lo pair ----------------
__global__ void gather_f32_kernel(const float* __restrict__ feat, const int* __restrict__ nn,
                                  const int* __restrict__ kint,
                                  unsigned short* __restrict__ Sh,
                                  unsigned short* __restrict__ Sl) {
  int idx = blockIdx.x * 256 + threadIdx.x;
  int node = idx / 24, c4 = idx % 24;
  int kc = kint[node];
  const int* nr = nn + (size_t)node * KNN;
  float4 acc = make_float4(0.f, 0.f, 0.f, 0.f);
  for (int k = 0; k < kc; k++) {
    int j = nr[k];
    float4 v = ((const float4*)(feat + (size_t)j * C))[c4];
    acc.x += v.x; acc.y += v.y; acc.z += v.z; acc.w += v.w;
  }
  ushort4 h, l;
  h.x = f2bf(acc.x); l.x = f2bf(acc.x - bf2f(h.x));
  h.y = f2bf(acc.y); l.y = f2bf(acc.y - bf2f(h.y));
  h.z = f2bf(acc.z); l.z = f2bf(acc.z - bf2f(h.z));
  h.w = f2bf(acc.w); l.w = f2bf(acc.w - bf2f(h.w));
  ((ushort4*)(Sh + (size_t)node * C))[c4] = h;
  ((ushort4*)(Sl + (size_t)node * C))[c4] = l;
}

// ---------------- gather-sum (bf16-pair feat) -> bf16 hi/lo pair ----------------
__global__ void gather_bf_kernel(const unsigned short* __restrict__ fh,
                                 const unsigned short* __restrict__ fl,
                                 const int* __restrict__ nn, const int* __restrict__ kint,
                                 unsigned short* __restrict__ Sh,
                                 unsigned short* __restrict__ Sl) {
  int idx = blockIdx.x * 256 + threadIdx.x;
  int node = idx / 24, c4 = idx % 24;
  int kc = kint[node];
  const int* nr = nn + (size_t)node * KNN;
  float4 acc = make_float4(0.f, 0.f, 0.f, 0.f);
  for (int k = 0; k < kc; k++) {
    int j = nr[k];
    ushort4 h = ((const ushort4*)(fh + (size_t)j * C))[c4];
    ushort4 l = ((const ushort4*)(fl + (size_t)j * C))[c4];
    acc.x += bf2f(h.x) + bf2f(l.x);
    acc.y += bf2f(h.y) + bf2f(l.y);
    acc.z += bf2f(h.z) + bf2f(l.z);
    acc.w += bf2f(h.w) + bf2f(l.w);
  }
  ushort4 h, l;
  h.x = f2bf(acc.x); l.x = f2bf(acc.x - bf2f(h.x));
  h.y = f2bf(acc.y); l.y = f2bf(acc.y - bf2f(h.y));
  h.z = f2bf(acc.z); l.z = f2bf(acc.z - bf2f(h.z));
  h.w = f2bf(acc.w); l.w = f2bf(acc.w - bf2f(h.w));
  ((ushort4*)(Sh + (size_t)node * C))[c4] = h;
  ((ushort4*)(Sl + (size_t)node * C))[c4] = l;
}

// ---------------- MFMA EdgeConv GEMM: 1 wave = 32 rows x 32 cols ----------------
__global__ __launch_bounds__(192) void mfma_ec_kernel(
    const unsigned short* __restrict__ A0h, const unsigned short* __restrict__ A0l,
    const unsigned short* __restrict__ A1h, const unsigned short* __restrict__ A1l,
    const unsigned short* __restrict__ Bth, const unsigned short* __restrict__ Btl,
    const float* __restrict__ rs, const float* __restrict__ bias, int relu,
    unsigned short* __restrict__ Oh, unsigned short* __restrict__ Ol) {
  __shared__ float rsL[32];
  __shared__ float bL[96];
  int tid = threadIdx.x, lane = tid & 63, wv = tid >> 6;
  int m0 = blockIdx.x * 32;
  if (tid < 32) rsL[tid] = rs[m0 + tid];
  if (tid < 96) bL[tid] = bias[tid];
  __syncthreads();

  int koff = (lane >> 5) * 8;
  int arow = m0 + (lane & 31);
  const unsigned short* a0h = A0h + (size_t)arow * 96 + koff;
  const unsigned short* a0l = A0l + (size_t)arow * 96 + koff;
  const unsigned short* a1h = A1h + (size_t)arow * 96 + koff;
  const unsigned short* a1l = A1l + (size_t)arow * 96 + koff;
  int n = wv * 32 + (lane & 31);

  f32x16 acc1 = (f32x16){0.f, 0.f, 0.f, 0.f, 0.f, 0.f, 0.f, 0.f,
                         0.f, 0.f, 0.f, 0.f, 0.f, 0.f, 0.f, 0.f};
  f32x16 acc2 = acc1;

#pragma unroll
  for (int c = 0; c < 6; c++) {
    s16x8 ah = *(const s16x8*)(a0h + c * 16);
    s16x8 al = *(const s16x8*)(a0l + c * 16);
    size_t bo = (size_t)n * 192 + c * 16 + koff;
    s16x8 bh = *(const s16x8*)(Bth + bo);
    s16x8 bl = *(const s16x8*)(Btl + bo);
    acc1 = __builtin_amdgcn_mfma_f32_32x32x16_bf16(ah, bh, acc1, 0, 0, 0);
    acc1 = __builtin_amdgcn_mfma_f32_32x32x16_bf16(al, bh, acc1, 0, 0, 0);
    acc1 = __builtin_amdgcn_mfma_f32_32x32x16_bf16(ah, bl, acc1, 0, 0, 0);
  }
#pragma unroll
  for (int c = 6; c < 12; c++) {
    s16x8 ah = *(const s16x8*)(a1h + (c - 6) * 16);
    s16x8 al = *(const s16x8*)(a1l + (c - 6) * 16);
    size_t bo = (size_t)n * 192 + c * 16 + koff;
    s16x8 bh = *(const s16x8*)(Bth + bo);
    s16x8 bl = *(const s16x8*)(Btl + bo);
    acc2 = __builtin_amdgcn_mfma_f32_32x32x16_bf16(ah, bh, acc2, 0, 0, 0);
    acc2 = __builtin_amdgcn_mfma_f32_32x32x16_bf16(al, bh, acc2, 0, 0, 0);
    acc2 = __builtin_amdgcn_mfma_f32_32x32x16_bf16(ah, bl, acc2, 0, 0, 0);
  }

  float bn = bL[n];
#pragma unroll
  for (int reg = 0; reg < 16; reg++) {
    int rl = (reg & 3) + 8 * (reg >> 2) + 4 * (lane >> 5);
    int r = m0 + rl;
    float v = rsL[rl] * (acc1[reg] + bn) + acc2[reg];
    if (relu) v = fmaxf(v, 0.f);
    unsigned short h = f2bf(v);
    Oh[(size_t)r * 96 + n] = h;
    Ol[(size_t)r * 96 + n] = f2bf(v - bf2f(h));
  }
}

// ---------------- MFMA final GEMM + transpose-store: grid (784, 2), block 192 ----
__global__ __launch_bounds__(192) void mfma_final_kernel(
    const unsigned short* __restrict__ A0h, const unsigned short* __restrict__ A0l,
    const unsigned short* __restrict__ A1h, const unsigned short* __restrict__ A1l,
    const unsigned short* __restrict__ Bth, const unsigned short* __restrict__ Btl,
    const float* __restrict__ bias, float* __restrict__ out) {
  __shared__ float bL[96];
  __shared__ float tt[3][32][33];
  int tid = threadIdx.x, lane = tid & 63, wv = tid >> 6;
  int m0 = blockIdx.x * 32;
  int n0 = blockIdx.y * 96;
  if (tid < 96) bL[tid] = bias[n0 + tid];
  __syncthreads();

  int koff = (lane >> 5) * 8;
  int arow = m0 + (lane & 31);
  const unsigned short* a0h = A0h + (size_t)arow * 96 + koff;
  const unsigned short* a0l = A0l + (size_t)arow * 96 + koff;
  const unsigned short* a1h = A1h + (size_t)arow * 96 + koff;
  const unsigned short* a1l = A1l + (size_t)arow * 96 + koff;
  int nloc = lane & 31;
  int n = n0 + wv * 32 + nloc;

  f32x16 acc = (f32x16){0.f, 0.f, 0.f, 0.f, 0.f, 0.f, 0.f, 0.f,
                        0.f, 0.f, 0.f, 0.f, 0.f, 0.f, 0.f, 0.f};
#pragma unroll
  for (int c = 0; c < 12; c++) {
    s16x8 ah, al;
    if (c < 6) {
      ah = *(const s16x8*)(a0h + c * 16);
      al = *(const s16x8*)(a0l + c * 16);
    } else {
      ah = *(const s16x8*)(a1h + (c - 6) * 16);
      al = *(const s16x8*)(a1l + (c - 6) * 16);
    }
    size_t bo = (size_t)n * 192 + c * 16 + koff;
    s16x8 bh = *(const s16x8*)(Bth + bo);
    s16x8 bl = *(const s16x8*)(Btl + bo);
    acc = __builtin_amdgcn_mfma_f32_32x32x16_bf16(ah, bh, acc, 0, 0, 0);
    acc = __builtin_amdgcn_mfma_f32_32x32x16_bf16(al, bh, acc, 0, 0, 0);
    acc = __builtin_amdgcn_mfma_f32_32x32x16_bf16(ah, bl, acc, 0, 0, 0);
  }

  float bn = bL[wv * 32 + nloc];
#pragma unroll
  for (int reg = 0; reg < 16; reg++) {
    int rl = (reg & 3) + 8 * (reg >> 2) + 4 * (lane >> 5);
    tt[wv][nloc][rl] = fmaxf(acc[reg] + bn, 0.f);
  }
  __builtin_amdgcn_s_waitcnt(0);  // wave-local LDS write->read (R12-proven)
  int gbase = m0 + nloc;  // 32-row tile lies within one batch (3136 % 32 == 0)
  int bb = gbase / NPB, nidx = gbase % NPB;
#pragma unroll
  for (int i = 0; i < 16; i++) {
    int nl = 2 * i + (lane >> 5);
    float v = tt[wv][nl][nloc];
    int ng = n0 + wv * 32 + nl;
    out[(size_t)bb * COUT * NPB + (size_t)ng * NPB + nidx] = v;
  }
}

// ---------------- fp32 GEMM (h64 head only) ----------------
__global__ __launch_bounds__(256) void gemm_kernel(
    const float* __restrict__ A0, int Ktot, const float* __restrict__ B, int ldb,
    const float* __restrict__ bias, float* __restrict__ Cc, int N, int relu) {
  __shared__ float As[16][68];
  __shared__ float Bs[16][68];
  int tid = threadIdx.x;
  int tx = tid & 15, ty = tid >> 4;
  int row0 = blockIdx.x * 64, col0 = blockIdx.y * 64;
  float acc[4][4] = {};
  int ai = tid >> 2;
  int ak = (tid & 3) * 4;
  int bk = tid >> 4;
  int bj = (tid & 15) * 4;

  for (int k0 = 0; k0 < Ktot; k0 += 16) {
    {
      int r = row0 + ai;
      float4 v = *(const float4*)(A0 + (size_t)r * Ktot + k0 + ak);
      As[ak + 0][ai] = v.x;
      As[ak + 1][ai] = v.y;
      As[ak + 2][ai] = v.z;
      As[ak + 3][ai] = v.w;
    }
    {
      int kg = k0 + bk;
      int j = col0 + bj;
      float4 v = make_float4(0.f, 0.f, 0.f, 0.f);
      if (j < N) v = *(const float4*)(B + (size_t)kg * ldb + j);
      *(float4*)&Bs[bk][bj] = v;
    }
    __syncthreads();
#pragma unroll
    for (int kk = 0; kk < 16; kk++) {
      float4 av = *(const float4*)&As[kk][ty * 4];
      float4 bv = *(const float4*)&Bs[kk][tx * 4];
      acc[0][0] += av.x * bv.x; acc[0][1] += av.x * bv.y; acc[0][2] += av.x * bv.z; acc[0][3] += av.x * bv.w;
      acc[1][0] += av.y * bv.x; acc[1][1] += av.y * bv.y; acc[1][2] += av.y * bv.z; acc[1][3] += av.y * bv.w;
      acc[2][0] += av.z * bv.x; acc[2][1] += av.z * bv.y; acc[2][2] += av.z * bv.z; acc[2][3] += av.z * bv.w;
      acc[3][0] += av.w * bv.x; acc[3][1] += av.w * bv.y; acc[3][2] += av.w * bv.z; acc[3][3] += av.w * bv.w;
    }
    __syncthreads();
  }
#pragma unroll
  for (int ii = 0; ii < 4; ii++) {
    int r = row0 + ty * 4 + ii;
#pragma unroll
    for (int jj = 0; jj < 4; jj++) {
      int j = col0 + tx * 4 + jj;
      if (j >= N) continue;
      float v = acc[ii][jj] + bias[j];
      if (relu) v = fmaxf(v, 0.f);
      Cc[(size_t)r * N + j] = v;
    }
  }
}

extern "C" void kernel_launch(void* const* d_in, const int* in_sizes, int n_in,
                              void* d_out, int out_size, void* d_ws, size_t ws_size,
                              hipStream_t stream) {
  const float* x      = (const float*)d_in[0];
  const float* kmap_w = (const float*)d_in[1];
  const float* kmap_b = (const float*)d_in[2];
  const float* kfc_w  = (const float*)d_in[3];
  const float* kfc_b  = (const float*)d_in[4];
  const float* kmu_w  = (const float*)d_in[5];
  const float* kmu_b  = (const float*)d_in[6];
  const float* kdec_w = (const float*)d_in[7];
  const float* kdec_b = (const float*)d_in[8];
  const float* ec1_w  = (const float*)d_in[9];
  const float* ec1_b  = (const float*)d_in[10];
  const float* ec2_w  = (const float*)d_in[11];
  const float* ec2_b  = (const float*)d_in[12];
  const float* fc_w   = (const float*)d_in[13];
  const float* fc_b   = (const float*)d_in[14];
  const float* io_w   = (const float*)d_in[15];
  const float* io_b   = (const float*)d_in[16];
  const float* up_w   = (const float*)d_in[17];
  const float* up_b   = (const float*)d_in[18];

  // ---- workspace layout (liveness-aliased) ----
  char* ws = (char*)d_ws;
  size_t off = 0;
  auto alloc = [&](size_t bytes) -> void* {
    void* p = ws + off;
    off += (bytes + 255) & ~(size_t)255;
    return p;
  };
  const size_t HBF = (size_t)NODES * C * 2;  // bf16 plane (256-aligned)
  float* xf   = (float*)alloc((size_t)NODES * C * 4);
  float* sqb  = (float*)alloc((size_t)NODES * 4);
  float* rs   = (float*)alloc((size_t)NODES * 4);
  int*   kint = (int*)alloc((size_t)NODES * 4);
  int*   nn   = (int*)alloc((size_t)NODES * KNN * 4);
  unsigned short* xh = (unsigned short*)alloc(HBF);
  unsigned short* xl = (unsigned short*)alloc(HBF);
  unsigned short* Sh = (unsigned short*)alloc(HBF);
  unsigned short* Sl = (unsigned short*)alloc(HBF);
  char* region = (char*)alloc((size_t)NODES * COUT * 4);
  // region timeline: h64buf(6.4M) -> pk_i(4.8M) -> h1 pair -> h2 pair (serial)
  float* h64buf = (float*)region;
  int*   pk_i   = (int*)region;
  unsigned short* h1h = (unsigned short*)region;
  unsigned short* h1l = (unsigned short*)(region + HBF);
  unsigned short* h2h = (unsigned short*)(region + 2 * HBF);
  unsigned short* h2l = (unsigned short*)(region + 3 * HBF);
  float* WkP = (float*)alloc(96 * 64 * 4);
  float* bkP = (float*)alloc(64 * 4);
  float* WdP = (float*)alloc(64 * 9 * 4);
  float* bdP = (float*)alloc(16 * 4);
  float* bPf = (float*)alloc(192 * 4);
  unsigned short* B1h = (unsigned short*)alloc(96 * 192 * 2);
  unsigned short* B1l = (unsigned short*)alloc(96 * 192 * 2);
  unsigned short* B2h = (unsigned short*)alloc(96 * 192 * 2);
  unsigned short* B2l = (unsigned short*)alloc(96 * 192 * 2);
  unsigned short* BFh = (unsigned short*)alloc(192 * 192 * 2);
  unsigned short* BFl = (unsigned short*)alloc(192 * 192 * 2);

  transpose_kernel<<<dim3(98, 3, 8), dim3(32, 8), 0, stream>>>(x, xf);
  sqsplit_kernel<<<98, 256, 0, stream>>>(xf, sqb, xh, xl);

  // ---- one fused fold launch ----
  fold_all_kernel<<<883, 256, 0, stream>>>(
      kmap_w, kmap_b, kfc_w, kfc_b, kmu_w, kmu_b, kdec_w, kdec_b, ec1_w, ec2_w,
      io_w, io_b, fc_w, fc_b, up_w, up_b,
      WkP, bkP, WdP, bdP, bPf, B1h, B1l, B2h, B2l, BFh, BFl);

  // ---- VAE head: h64 GEMM + argmax -> kint, rs ----
  gemm_kernel<<<dim3(392, 1), 256, 0, stream>>>(xf, 96, WkP, 64, bkP, h64buf, 64, 1);
  argmax9_kernel<<<98, 256, 0, stream>>>(h64buf, WdP, bdP, kint, rs);

  // ---- kNN filter (operand-swapped, in-register scan) + exact rescore ----
  knn_mfma_kernel<<<dim3(49, 8, MSPLIT), 256, 0, stream>>>(xh, xl, sqb, pk_i);
  rescore_kernel<<<6272, 256, 0, stream>>>(xf, sqb, pk_i, nn);

  // ---- EdgeConv layer 1 (relu) ----
  gather_f32_kernel<<<2352, 256, 0, stream>>>(xf, nn, kint, Sh, Sl);
  mfma_ec_kernel<<<784, 192, 0, stream>>>(xh, xl, Sh, Sl, B1h, B1l, rs, ec1_b, 1,
                                          h1h, h1l);
  // ---- EdgeConv layer 2 (no relu) ----
  gather_bf_kernel<<<2352, 256, 0, stream>>>(h1h, h1l, nn, kint, Sh, Sl);
  mfma_ec_kernel<<<784, 192, 0, stream>>>(h1h, h1l, Sh, Sl, B2h, B2l, rs, ec2_b, 0,
                                          h2h, h2l);
  // ---- final folded GEMM + transpose-store ----
  mfma_final_kernel<<<dim3(784, 2), 192, 0, stream>>>(xh, xl, h2h, h2l, BFh, BFl,
                                                      bPf, (float*)d_out);
}